// Round 1
// baseline (959.988 us; speedup 1.0000x reference)
//
#include <hip/hip_runtime.h>

#define NLOCAL 16384
#define NEDGES 131072
#define NREL   16
#define DIM    256
#define NQ     4096

typedef __bf16 bf16x8 __attribute__((ext_vector_type(8)));
typedef float  f32x4  __attribute__((ext_vector_type(4)));
typedef unsigned short u16x4 __attribute__((ext_vector_type(4)));

static __device__ __forceinline__ unsigned short f2bf(float f) {
    union { float f; unsigned u; } v; v.f = f;
    unsigned r = v.u + 0x7FFFu + ((v.u >> 16) & 1u);
    return (unsigned short)(r >> 16);
}

// ---------------- gather x0 = emb[entity_ids] ----------------
__global__ void k_gather(const float* __restrict__ emb, const int* __restrict__ ids,
                         float* __restrict__ x0) {
    int gid = blockIdx.x * blockDim.x + threadIdx.x;   // 16384*64 threads
    int i = gid >> 6, c4 = gid & 63;
    int e = ids[i];
    ((f32x4*)x0)[(size_t)i * 64 + c4] = ((const f32x4*)emb)[(size_t)e * 64 + c4];
}

// ---------------- transpose+bf16 weights: WT[r][o][k] = bf16(W[r][k][o]) ----------------
__global__ void k_transpose(const float* __restrict__ W, unsigned short* __restrict__ WT) {
    __shared__ float t[64][65];
    int blk = blockIdx.x;
    int r  = blk >> 4;
    int tr = blk & 15;
    int tk = (tr >> 2) << 6;   // k tile origin
    int to = (tr & 3) << 6;    // o tile origin
    const float* Wr = W + (size_t)r * DIM * DIM;
    unsigned short* WTr = WT + (size_t)r * DIM * DIM;
    #pragma unroll
    for (int it = 0; it < 16; ++it) {
        int el = it * 256 + threadIdx.x;
        int row = el >> 6, col = el & 63;
        t[row][col] = Wr[(size_t)(tk + row) * DIM + to + col];
    }
    __syncthreads();
    #pragma unroll
    for (int it = 0; it < 16; ++it) {
        int el = it * 256 + threadIdx.x;
        int row = el >> 6, col = el & 63;
        WTr[(size_t)(to + row) * DIM + tk + col] = f2bf(t[col][row]);
    }
}

// ---------------- per-(tgt,rel) counts + per-rel histogram ----------------
__global__ void k_hist(const int* __restrict__ eidx, const int* __restrict__ etype,
                       unsigned int* __restrict__ cnt, int* __restrict__ meta) {
    __shared__ int h[NREL];
    if (threadIdx.x < NREL) h[threadIdx.x] = 0;
    __syncthreads();
    int e = blockIdx.x * blockDim.x + threadIdx.x;
    if (e < NEDGES) {
        int rel = etype[e];
        int tgt = eidx[NEDGES + e];
        atomicAdd(&cnt[tgt * NREL + rel], 1u);
        atomicAdd(&h[rel], 1);
    }
    __syncthreads();
    if (threadIdx.x < NREL) atomicAdd(&meta[threadIdx.x], h[threadIdx.x]);
}

// ---------------- scan: seg_start (64-aligned regions) + cursors ----------------
__global__ void k_scan(int* __restrict__ meta) {
    if (threadIdx.x == 0) {
        int s = 0;
        for (int r = 0; r < NREL; ++r) {
            meta[16 + r] = s;
            s += (meta[r] + 63) & ~63;
        }
        meta[32] = s;
        for (int r = 0; r < NREL; ++r) meta[33 + r] = meta[16 + r];
    }
}

// ---------------- place edges into relation-sorted arrays ----------------
__global__ void k_place(const int* __restrict__ eidx, const int* __restrict__ etype,
                        int* __restrict__ meta, int* __restrict__ ssrc, int* __restrict__ stgt) {
    int e = blockIdx.x * blockDim.x + threadIdx.x;
    int lane = threadIdx.x & 63;
    int rel = (e < NEDGES) ? etype[e] : -1;
    for (int r = 0; r < NREL; ++r) {
        unsigned long long m = __ballot(rel == r);
        if (m) {
            int leader = __ffsll(m) - 1;
            int base = 0;
            if (lane == leader) base = atomicAdd(&meta[33 + r], (int)__popcll(m));
            base = __shfl(base, leader);
            if (rel == r) {
                int pos = base + (int)__popcll(m & ((1ull << lane) - 1ull));
                ssrc[pos] = eidx[e];
                stgt[pos] = eidx[NEDGES + e];
            }
        }
    }
}

// ---------------- root GEMM: Y = X @ rootT^T + bias (writes all of Y) ----------------
__launch_bounds__(256)
__global__ void k_gemm_root(const float* __restrict__ X, const unsigned short* __restrict__ BT,
                            const float* __restrict__ bias, float* __restrict__ Y) {
    __shared__ __align__(16) unsigned short As[64][72];
    __shared__ __align__(16) unsigned short Bs[256][72];
    int tid = threadIdx.x;
    int wave = tid >> 6, lane = tid & 63;
    int l16 = lane & 15, grp = lane >> 4;
    int bm = blockIdx.x;

    f32x4 acc[4][4];
    #pragma unroll
    for (int i = 0; i < 4; ++i)
        #pragma unroll
        for (int j = 0; j < 4; ++j) acc[i][j] = f32x4{0.f, 0.f, 0.f, 0.f};

    const f32x4* X4 = (const f32x4*)X;
    for (int kt = 0; kt < 4; ++kt) {
        #pragma unroll
        for (int it = 0; it < 4; ++it) {
            int flat = it * 256 + tid;
            int row = flat >> 4, c4 = flat & 15;
            f32x4 v = X4[(size_t)(bm * 64 + row) * 64 + kt * 16 + c4];
            u16x4 u;
            u[0] = f2bf(v[0]); u[1] = f2bf(v[1]); u[2] = f2bf(v[2]); u[3] = f2bf(v[3]);
            *(u16x4*)&As[row][c4 * 4] = u;
        }
        #pragma unroll
        for (int it = 0; it < 16; ++it) {
            int flat = it * 256 + tid;
            int n = flat >> 4, c4 = flat & 15;
            u16x4 u = *(const u16x4*)&BT[(size_t)n * DIM + kt * 64 + c4 * 4];
            *(u16x4*)&Bs[n][c4 * 4] = u;
        }
        __syncthreads();
        #pragma unroll
        for (int kk = 0; kk < 2; ++kk) {
            bf16x8 a[4], b[4];
            #pragma unroll
            for (int i = 0; i < 4; ++i)
                a[i] = *(const bf16x8*)&As[i * 16 + l16][kk * 32 + grp * 8];
            #pragma unroll
            for (int j = 0; j < 4; ++j)
                b[j] = *(const bf16x8*)&Bs[wave * 64 + j * 16 + l16][kk * 32 + grp * 8];
            #pragma unroll
            for (int i = 0; i < 4; ++i)
                #pragma unroll
                for (int j = 0; j < 4; ++j)
                    acc[i][j] = __builtin_amdgcn_mfma_f32_16x16x32_bf16(a[i], b[j], acc[i][j], 0, 0, 0);
        }
        __syncthreads();
    }
    #pragma unroll
    for (int i = 0; i < 4; ++i)
        #pragma unroll
        for (int reg = 0; reg < 4; ++reg) {
            int row = i * 16 + grp * 4 + reg;
            int gr = bm * 64 + row;
            #pragma unroll
            for (int j = 0; j < 4; ++j) {
                int col = wave * 64 + j * 16 + l16;
                Y[(size_t)gr * DIM + col] = acc[i][j][reg] + bias[col];
            }
        }
}

// ---------------- edge GEMM: Y[tgt] += (x[src] @ W[rel]) * rcnt ----------------
__launch_bounds__(256)
__global__ void k_gemm_edge(const float* __restrict__ X, const unsigned short* __restrict__ WT,
                            const int* __restrict__ ssrc, const int* __restrict__ stgt,
                            const unsigned int* __restrict__ cnt, const int* __restrict__ meta,
                            float* __restrict__ Y) {
    int base = blockIdx.x * 64;
    if (base >= meta[32]) return;
    int rel = 0;
    while (rel < 15 && meta[16 + rel + 1] <= base) ++rel;
    const unsigned short* BT = WT + (size_t)rel * DIM * DIM;

    __shared__ __align__(16) unsigned short As[64][72];
    __shared__ __align__(16) unsigned short Bs[256][72];
    int tid = threadIdx.x;
    int wave = tid >> 6, lane = tid & 63;
    int l16 = lane & 15, grp = lane >> 4;

    f32x4 acc[4][4];
    #pragma unroll
    for (int i = 0; i < 4; ++i)
        #pragma unroll
        for (int j = 0; j < 4; ++j) acc[i][j] = f32x4{0.f, 0.f, 0.f, 0.f};

    const f32x4* X4 = (const f32x4*)X;
    for (int kt = 0; kt < 4; ++kt) {
        #pragma unroll
        for (int it = 0; it < 4; ++it) {
            int flat = it * 256 + tid;
            int row = flat >> 4, c4 = flat & 15;
            int s = ssrc[base + row];
            u16x4 u;
            if (s >= 0) {
                f32x4 v = X4[(size_t)s * 64 + kt * 16 + c4];
                u[0] = f2bf(v[0]); u[1] = f2bf(v[1]); u[2] = f2bf(v[2]); u[3] = f2bf(v[3]);
            } else {
                u[0] = 0; u[1] = 0; u[2] = 0; u[3] = 0;
            }
            *(u16x4*)&As[row][c4 * 4] = u;
        }
        #pragma unroll
        for (int it = 0; it < 16; ++it) {
            int flat = it * 256 + tid;
            int n = flat >> 4, c4 = flat & 15;
            u16x4 u = *(const u16x4*)&BT[(size_t)n * DIM + kt * 64 + c4 * 4];
            *(u16x4*)&Bs[n][c4 * 4] = u;
        }
        __syncthreads();
        #pragma unroll
        for (int kk = 0; kk < 2; ++kk) {
            bf16x8 a[4], b[4];
            #pragma unroll
            for (int i = 0; i < 4; ++i)
                a[i] = *(const bf16x8*)&As[i * 16 + l16][kk * 32 + grp * 8];
            #pragma unroll
            for (int j = 0; j < 4; ++j)
                b[j] = *(const bf16x8*)&Bs[wave * 64 + j * 16 + l16][kk * 32 + grp * 8];
            #pragma unroll
            for (int i = 0; i < 4; ++i)
                #pragma unroll
                for (int j = 0; j < 4; ++j)
                    acc[i][j] = __builtin_amdgcn_mfma_f32_16x16x32_bf16(a[i], b[j], acc[i][j], 0, 0, 0);
        }
        __syncthreads();
    }
    #pragma unroll
    for (int i = 0; i < 4; ++i)
        #pragma unroll
        for (int reg = 0; reg < 4; ++reg) {
            int row = i * 16 + grp * 4 + reg;
            int e = base + row;
            int s = ssrc[e];
            if (s < 0) continue;
            int tgt = stgt[e];
            float rc = 1.0f / fmaxf((float)cnt[tgt * NREL + rel], 1.0f);
            float* orow = Y + (size_t)tgt * DIM;
            #pragma unroll
            for (int j = 0; j < 4; ++j) {
                int col = wave * 64 + j * 16 + l16;
                unsafeAtomicAdd(&orow[col], acc[i][j][reg] * rc);
            }
        }
}

// ---------------- readout: out[q] += x2[i] ----------------
__global__ void k_readout(const float* __restrict__ X2, const int* __restrict__ bids,
                          float* __restrict__ out) {
    int gid = blockIdx.x * blockDim.x + threadIdx.x;  // 16384*64
    int i = gid >> 6, c4 = gid & 63;
    int q = bids[i];
    f32x4 v = ((const f32x4*)X2)[(size_t)i * 64 + c4];
    #pragma unroll
    for (int j = 0; j < 4; ++j)
        unsafeAtomicAdd(&out[(size_t)q * DIM + c4 * 4 + j], v[j]);
}

extern "C" void kernel_launch(void* const* d_in, const int* in_sizes, int n_in,
                              void* d_out, int out_size, void* d_ws, size_t ws_size,
                              hipStream_t stream) {
    const float* emb   = (const float*)d_in[0];
    const float* w1    = (const float*)d_in[1];
    const float* root1 = (const float*)d_in[2];
    const float* b1    = (const float*)d_in[3];
    const float* w2    = (const float*)d_in[4];
    const float* root2 = (const float*)d_in[5];
    const float* b2    = (const float*)d_in[6];
    const int* eidx    = (const int*)d_in[7];
    const int* etype   = (const int*)d_in[8];
    const int* eids    = (const int*)d_in[9];
    const int* bids    = (const int*)d_in[10];
    float* out = (float*)d_out;

    char* ws = (char*)d_ws;
    float* x0 = (float*)(ws + (size_t)(0 << 20));
    float* x1 = (float*)(ws + (size_t)(16 << 20));
    float* x2 = (float*)(ws + (size_t)(32 << 20));
    unsigned short* WT1 = (unsigned short*)(ws + (size_t)(48 << 20));  // 2 MB
    unsigned short* rT1 = (unsigned short*)(ws + (size_t)(50 << 20));  // 128 KB
    unsigned short* WT2 = (unsigned short*)(ws + (size_t)(51 << 20));  // 2 MB
    unsigned short* rT2 = (unsigned short*)(ws + (size_t)(53 << 20));  // 128 KB
    unsigned int*   cnt = (unsigned int*)(ws + (size_t)(54 << 20));    // 1 MB
    int*           meta = (int*)(ws + (size_t)(55 << 20));             // 256 B
    int*           ssrc = (int*)(ws + (size_t)(55 << 20) + 65536);     // 528 KB
    int*           stgt = (int*)(ws + (size_t)(56 << 20));             // 528 KB

    const int NBLK_EDGE = (NEDGES + NREL * 64) / 64;  // 2064

    hipMemsetAsync(cnt, 0, (size_t)NLOCAL * NREL * 4, stream);
    hipMemsetAsync(meta, 0, 256, stream);
    hipMemsetAsync(ssrc, 0xFF, (size_t)(NEDGES + NREL * 64) * 4, stream);
    hipMemsetAsync(out, 0, (size_t)NQ * DIM * 4, stream);

    k_gather<<<4096, 256, 0, stream>>>(emb, eids, x0);
    k_transpose<<<NREL * 16, 256, 0, stream>>>(w1, WT1);
    k_transpose<<<16, 256, 0, stream>>>(root1, rT1);
    k_transpose<<<NREL * 16, 256, 0, stream>>>(w2, WT2);
    k_transpose<<<16, 256, 0, stream>>>(root2, rT2);
    k_hist<<<NEDGES / 256, 256, 0, stream>>>(eidx, etype, cnt, meta);
    k_scan<<<1, 64, 0, stream>>>(meta);
    k_place<<<NEDGES / 256, 256, 0, stream>>>(eidx, etype, meta, ssrc, stgt);

    // layer 1
    k_gemm_root<<<NLOCAL / 64, 256, 0, stream>>>(x0, rT1, b1, x1);
    k_gemm_edge<<<NBLK_EDGE, 256, 0, stream>>>(x0, WT1, ssrc, stgt, cnt, meta, x1);
    // layer 2
    k_gemm_root<<<NLOCAL / 64, 256, 0, stream>>>(x1, rT2, b2, x2);
    k_gemm_edge<<<NBLK_EDGE, 256, 0, stream>>>(x1, WT2, ssrc, stgt, cnt, meta, x2);

    k_readout<<<4096, 256, 0, stream>>>(x2, bids, out);
}

// Round 3
// 620.779 us; speedup vs baseline: 1.5464x; 1.5464x over previous
//
#include <hip/hip_runtime.h>

#define NLOCAL 16384
#define NEDGES 131072
#define NREL   16
#define DIM    256
#define NQ     4096
#define NBLKS  512   // NEDGES / 256

typedef __bf16 bf16x8 __attribute__((ext_vector_type(8)));
typedef float  f32x4  __attribute__((ext_vector_type(4)));
typedef unsigned short u16x4 __attribute__((ext_vector_type(4)));

static __device__ __forceinline__ unsigned short f2bf(float f) {
    union { float f; unsigned u; } v; v.f = f;
    unsigned r = v.u + 0x7FFFu + ((v.u >> 16) & 1u);
    return (unsigned short)(r >> 16);
}

// ---------------- gather x0 = emb[entity_ids] ----------------
__global__ void k_gather(const float* __restrict__ emb, const int* __restrict__ ids,
                         float* __restrict__ x0) {
    int gid = blockIdx.x * blockDim.x + threadIdx.x;   // 16384*64 threads
    int i = gid >> 6, c4 = gid & 63;
    int e = ids[i];
    ((f32x4*)x0)[(size_t)i * 64 + c4] = ((const f32x4*)emb)[(size_t)e * 64 + c4];
}

// ---------------- transpose+bf16 weights: WT[r][o][k] = bf16(W[r][k][o]) ----------------
__global__ void k_transpose(const float* __restrict__ W, unsigned short* __restrict__ WT) {
    __shared__ float t[64][65];
    int blk = blockIdx.x;
    int r  = blk >> 4;
    int tr = blk & 15;
    int tk = (tr >> 2) << 6;   // k tile origin
    int to = (tr & 3) << 6;    // o tile origin
    const float* Wr = W + (size_t)r * DIM * DIM;
    unsigned short* WTr = WT + (size_t)r * DIM * DIM;
    #pragma unroll
    for (int it = 0; it < 16; ++it) {
        int el = it * 256 + threadIdx.x;
        int row = el >> 6, col = el & 63;
        t[row][col] = Wr[(size_t)(tk + row) * DIM + to + col];
    }
    __syncthreads();
    #pragma unroll
    for (int it = 0; it < 16; ++it) {
        int el = it * 256 + threadIdx.x;
        int row = el >> 6, col = el & 63;
        WTr[(size_t)(to + row) * DIM + tk + col] = f2bf(t[col][row]);
    }
}

// ---------------- per-(tgt,rel) counts ----------------
__global__ void k_hist(const int* __restrict__ eidx, const int* __restrict__ etype,
                       unsigned int* __restrict__ cnt) {
    int e = blockIdx.x * blockDim.x + threadIdx.x;
    int rel = etype[e];
    int tgt = eidx[NEDGES + e];
    atomicAdd(&cnt[tgt * NREL + rel], 1u);
}

// ---------------- counting sort pass A: per-block relation histogram ----------------
__global__ void k_bhist(const int* __restrict__ etype, int* __restrict__ bh) {
    __shared__ int h[NREL];
    int tid = threadIdx.x;
    if (tid < NREL) h[tid] = 0;
    __syncthreads();
    int e = blockIdx.x * 256 + tid;
    atomicAdd(&h[etype[e]], 1);
    __syncthreads();
    if (tid < NREL) bh[tid * NBLKS + blockIdx.x] = h[tid];   // [rel][block]
}

// ---------------- counting sort pass B: exclusive scan + region bases ----------------
__global__ void k_scan2(int* __restrict__ bh, int* __restrict__ meta) {
    __shared__ int tot[NREL];
    int r = threadIdx.x;
    if (r < NREL) {
        int s = 0;
        for (int b = 0; b < NBLKS; ++b) { int v = bh[r * NBLKS + b]; bh[r * NBLKS + b] = s; s += v; }
        tot[r] = s;
    }
    __syncthreads();
    if (r == 0) {
        int s = 0;
        for (int q = 0; q < NREL; ++q) { meta[16 + q] = s; s += (tot[q] + 63) & ~63; }
        meta[32] = s;
    }
    __syncthreads();
    if (r < NREL) {
        int base = meta[16 + r];
        for (int b = 0; b < NBLKS; ++b) bh[r * NBLKS + b] += base;
    }
}

// ---------------- counting sort pass C: place via LDS cursors ----------------
__global__ void k_place2(const int* __restrict__ eidx, const int* __restrict__ etype,
                         const int* __restrict__ bh, int* __restrict__ ssrc,
                         int* __restrict__ stgt) {
    __shared__ int cur[NREL];
    int tid = threadIdx.x;
    if (tid < NREL) cur[tid] = bh[tid * NBLKS + blockIdx.x];
    __syncthreads();
    int e = blockIdx.x * 256 + tid;
    int rel = etype[e];
    int pos = atomicAdd(&cur[rel], 1);
    ssrc[pos] = eidx[e];
    stgt[pos] = eidx[NEDGES + e];
}

// ---------------- root GEMM: Y = X @ rootT^T + bias (writes all of Y) ----------------
__launch_bounds__(256)
__global__ void k_gemm_root(const float* __restrict__ X, const unsigned short* __restrict__ BT,
                            const float* __restrict__ bias, float* __restrict__ Y) {
    __shared__ __align__(16) unsigned short As[64][72];
    __shared__ __align__(16) unsigned short Bs[256][72];
    int tid = threadIdx.x;
    int wave = tid >> 6, lane = tid & 63;
    int l16 = lane & 15, grp = lane >> 4;
    int bm = blockIdx.x;

    f32x4 acc[4][4];
    #pragma unroll
    for (int i = 0; i < 4; ++i)
        #pragma unroll
        for (int j = 0; j < 4; ++j) acc[i][j] = f32x4{0.f, 0.f, 0.f, 0.f};

    const f32x4* X4 = (const f32x4*)X;
    for (int kt = 0; kt < 4; ++kt) {
        #pragma unroll
        for (int it = 0; it < 4; ++it) {
            int flat = it * 256 + tid;
            int row = flat >> 4, c4 = flat & 15;
            f32x4 v = X4[(size_t)(bm * 64 + row) * 64 + kt * 16 + c4];
            u16x4 u;
            u[0] = f2bf(v[0]); u[1] = f2bf(v[1]); u[2] = f2bf(v[2]); u[3] = f2bf(v[3]);
            *(u16x4*)&As[row][c4 * 4] = u;
        }
        #pragma unroll
        for (int it = 0; it < 16; ++it) {
            int flat = it * 256 + tid;
            int n = flat >> 4, c4 = flat & 15;
            u16x4 u = *(const u16x4*)&BT[(size_t)n * DIM + kt * 64 + c4 * 4];
            *(u16x4*)&Bs[n][c4 * 4] = u;
        }
        __syncthreads();
        #pragma unroll
        for (int kk = 0; kk < 2; ++kk) {
            bf16x8 a[4], b[4];
            #pragma unroll
            for (int i = 0; i < 4; ++i)
                a[i] = *(const bf16x8*)&As[i * 16 + l16][kk * 32 + grp * 8];
            #pragma unroll
            for (int j = 0; j < 4; ++j)
                b[j] = *(const bf16x8*)&Bs[wave * 64 + j * 16 + l16][kk * 32 + grp * 8];
            #pragma unroll
            for (int i = 0; i < 4; ++i)
                #pragma unroll
                for (int j = 0; j < 4; ++j)
                    acc[i][j] = __builtin_amdgcn_mfma_f32_16x16x32_bf16(a[i], b[j], acc[i][j], 0, 0, 0);
        }
        __syncthreads();
    }
    #pragma unroll
    for (int i = 0; i < 4; ++i)
        #pragma unroll
        for (int reg = 0; reg < 4; ++reg) {
            int row = i * 16 + grp * 4 + reg;
            int gr = bm * 64 + row;
            #pragma unroll
            for (int j = 0; j < 4; ++j) {
                int col = wave * 64 + j * 16 + l16;
                Y[(size_t)gr * DIM + col] = acc[i][j][reg] + bias[col];
            }
        }
}

// ---------------- edge GEMM: Y[tgt] += (x[src] @ W[rel]) * rcnt ----------------
__launch_bounds__(256)
__global__ void k_gemm_edge(const float* __restrict__ X, const unsigned short* __restrict__ WT,
                            const int* __restrict__ ssrc, const int* __restrict__ stgt,
                            const unsigned int* __restrict__ cnt, const int* __restrict__ meta,
                            float* __restrict__ Y) {
    int base = blockIdx.x * 64;
    if (base >= meta[32]) return;
    int rel = 0;
    while (rel < 15 && meta[16 + rel + 1] <= base) ++rel;
    const unsigned short* BT = WT + (size_t)rel * DIM * DIM;

    __shared__ __align__(16) unsigned short As[64][72];
    __shared__ __align__(16) unsigned short Bs[256][72];
    int tid = threadIdx.x;
    int wave = tid >> 6, lane = tid & 63;
    int l16 = lane & 15, grp = lane >> 4;

    f32x4 acc[4][4];
    #pragma unroll
    for (int i = 0; i < 4; ++i)
        #pragma unroll
        for (int j = 0; j < 4; ++j) acc[i][j] = f32x4{0.f, 0.f, 0.f, 0.f};

    const f32x4* X4 = (const f32x4*)X;
    for (int kt = 0; kt < 4; ++kt) {
        #pragma unroll
        for (int it = 0; it < 4; ++it) {
            int flat = it * 256 + tid;
            int row = flat >> 4, c4 = flat & 15;
            int s = ssrc[base + row];
            u16x4 u;
            if (s >= 0) {
                f32x4 v = X4[(size_t)s * 64 + kt * 16 + c4];
                u[0] = f2bf(v[0]); u[1] = f2bf(v[1]); u[2] = f2bf(v[2]); u[3] = f2bf(v[3]);
            } else {
                u[0] = 0; u[1] = 0; u[2] = 0; u[3] = 0;
            }
            *(u16x4*)&As[row][c4 * 4] = u;
        }
        #pragma unroll
        for (int it = 0; it < 16; ++it) {
            int flat = it * 256 + tid;
            int n = flat >> 4, c4 = flat & 15;
            u16x4 u = *(const u16x4*)&BT[(size_t)n * DIM + kt * 64 + c4 * 4];
            *(u16x4*)&Bs[n][c4 * 4] = u;
        }
        __syncthreads();
        #pragma unroll
        for (int kk = 0; kk < 2; ++kk) {
            bf16x8 a[4], b[4];
            #pragma unroll
            for (int i = 0; i < 4; ++i)
                a[i] = *(const bf16x8*)&As[i * 16 + l16][kk * 32 + grp * 8];
            #pragma unroll
            for (int j = 0; j < 4; ++j)
                b[j] = *(const bf16x8*)&Bs[wave * 64 + j * 16 + l16][kk * 32 + grp * 8];
            #pragma unroll
            for (int i = 0; i < 4; ++i)
                #pragma unroll
                for (int j = 0; j < 4; ++j)
                    acc[i][j] = __builtin_amdgcn_mfma_f32_16x16x32_bf16(a[i], b[j], acc[i][j], 0, 0, 0);
        }
        __syncthreads();
    }
    #pragma unroll
    for (int i = 0; i < 4; ++i)
        #pragma unroll
        for (int reg = 0; reg < 4; ++reg) {
            int row = i * 16 + grp * 4 + reg;
            int e = base + row;
            int s = ssrc[e];
            if (s < 0) continue;
            int tgt = stgt[e];
            float rc = 1.0f / fmaxf((float)cnt[tgt * NREL + rel], 1.0f);
            float* orow = Y + (size_t)tgt * DIM;
            #pragma unroll
            for (int j = 0; j < 4; ++j) {
                int col = wave * 64 + j * 16 + l16;
                unsafeAtomicAdd(&orow[col], acc[i][j][reg] * rc);
            }
        }
}

// ---------------- readout: out[q] += x2[i] ----------------
__global__ void k_readout(const float* __restrict__ X2, const int* __restrict__ bids,
                          float* __restrict__ out) {
    int gid = blockIdx.x * blockDim.x + threadIdx.x;  // 16384*64
    int i = gid >> 6, c4 = gid & 63;
    int q = bids[i];
    f32x4 v = ((const f32x4*)X2)[(size_t)i * 64 + c4];
    #pragma unroll
    for (int j = 0; j < 4; ++j)
        unsafeAtomicAdd(&out[(size_t)q * DIM + c4 * 4 + j], v[j]);
}

extern "C" void kernel_launch(void* const* d_in, const int* in_sizes, int n_in,
                              void* d_out, int out_size, void* d_ws, size_t ws_size,
                              hipStream_t stream) {
    const float* emb   = (const float*)d_in[0];
    const float* w1    = (const float*)d_in[1];
    const float* root1 = (const float*)d_in[2];
    const float* b1    = (const float*)d_in[3];
    const float* w2    = (const float*)d_in[4];
    const float* root2 = (const float*)d_in[5];
    const float* b2    = (const float*)d_in[6];
    const int* eidx    = (const int*)d_in[7];
    const int* etype   = (const int*)d_in[8];
    const int* eids    = (const int*)d_in[9];
    const int* bids    = (const int*)d_in[10];
    float* out = (float*)d_out;

    char* ws = (char*)d_ws;
    float* x0 = (float*)(ws + (size_t)(0 << 20));
    float* x1 = (float*)(ws + (size_t)(16 << 20));
    float* x2 = (float*)(ws + (size_t)(32 << 20));
    unsigned short* WT1 = (unsigned short*)(ws + (size_t)(48 << 20));  // 2 MB
    unsigned short* rT1 = (unsigned short*)(ws + (size_t)(50 << 20));  // 128 KB
    unsigned short* WT2 = (unsigned short*)(ws + (size_t)(51 << 20));  // 2 MB
    unsigned short* rT2 = (unsigned short*)(ws + (size_t)(53 << 20));  // 128 KB
    unsigned int*   cnt = (unsigned int*)(ws + (size_t)(54 << 20));    // 1 MB
    int*           meta = (int*)(ws + (size_t)(55 << 20));             // 256 B
    int*           ssrc = (int*)(ws + (size_t)(55 << 20) + 65536);     // 528 KB
    int*           stgt = (int*)(ws + (size_t)(56 << 20));             // 528 KB
    int*           bh   = (int*)(ws + (size_t)(57 << 20));             // 32 KB

    const int NBLK_EDGE = (NEDGES + NREL * 64) / 64;  // 2064

    hipMemsetAsync(cnt, 0, (size_t)NLOCAL * NREL * 4, stream);
    hipMemsetAsync(ssrc, 0xFF, (size_t)(NEDGES + NREL * 64) * 4, stream);
    hipMemsetAsync(out, 0, (size_t)NQ * DIM * 4, stream);

    k_gather<<<4096, 256, 0, stream>>>(emb, eids, x0);
    k_transpose<<<NREL * 16, 256, 0, stream>>>(w1, WT1);
    k_transpose<<<16, 256, 0, stream>>>(root1, rT1);
    k_transpose<<<NREL * 16, 256, 0, stream>>>(w2, WT2);
    k_transpose<<<16, 256, 0, stream>>>(root2, rT2);
    k_hist<<<NEDGES / 256, 256, 0, stream>>>(eidx, etype, cnt);
    k_bhist<<<NBLKS, 256, 0, stream>>>(etype, bh);
    k_scan2<<<1, 64, 0, stream>>>(bh, meta);
    k_place2<<<NBLKS, 256, 0, stream>>>(eidx, etype, bh, ssrc, stgt);

    // layer 1
    k_gemm_root<<<NLOCAL / 64, 256, 0, stream>>>(x0, rT1, b1, x1);
    k_gemm_edge<<<NBLK_EDGE, 256, 0, stream>>>(x0, WT1, ssrc, stgt, cnt, meta, x1);
    // layer 2
    k_gemm_root<<<NLOCAL / 64, 256, 0, stream>>>(x1, rT2, b2, x2);
    k_gemm_edge<<<NBLK_EDGE, 256, 0, stream>>>(x1, WT2, ssrc, stgt, cnt, meta, x2);

    k_readout<<<4096, 256, 0, stream>>>(x2, bids, out);
}

// Round 4
// 505.600 us; speedup vs baseline: 1.8987x; 1.2278x over previous
//
#include <hip/hip_runtime.h>
#include <hip/hip_bf16.h>

#define NLOCAL 16384
#define NEDGES 131072
#define NREL   16
#define DIM    256
#define NQ     4096
#define NBLKS  512   // NEDGES / 256

typedef __bf16 bf16x8 __attribute__((ext_vector_type(8)));
typedef float  f32x4  __attribute__((ext_vector_type(4)));
typedef unsigned short u16x8 __attribute__((ext_vector_type(8)));

static __device__ __forceinline__ unsigned short f2bf(float f) {
    union { float f; unsigned u; } v; v.f = f;
    unsigned r = v.u + 0x7FFFu + ((v.u >> 16) & 1u);
    return (unsigned short)(r >> 16);
}
static __device__ __forceinline__ float bf2f(unsigned short s) {
    union { unsigned u; float f; } v; v.u = ((unsigned)s) << 16;
    return v.f;
}

// ---------------- gather x0 = bf16(emb[entity_ids]) ----------------
__global__ void k_gather(const float* __restrict__ emb, const int* __restrict__ ids,
                         unsigned short* __restrict__ x0) {
    int gid = blockIdx.x * blockDim.x + threadIdx.x;   // 16384*32 threads
    int i = gid >> 5, c8 = gid & 31;                   // 8 cols per thread
    int e = ids[i];
    const f32x4* src = (const f32x4*)(emb + (size_t)e * DIM + c8 * 8);
    f32x4 a = src[0], b = src[1];
    u16x8 u;
    u[0] = f2bf(a[0]); u[1] = f2bf(a[1]); u[2] = f2bf(a[2]); u[3] = f2bf(a[3]);
    u[4] = f2bf(b[0]); u[5] = f2bf(b[1]); u[6] = f2bf(b[2]); u[7] = f2bf(b[3]);
    *(u16x8*)&x0[(size_t)i * DIM + c8 * 8] = u;
}

// ---------------- transpose+bf16 all weights in one launch ----------------
__global__ void k_transpose_all(const float* __restrict__ w1, const float* __restrict__ r1,
                                const float* __restrict__ w2, const float* __restrict__ r2,
                                unsigned short* __restrict__ WT1, unsigned short* __restrict__ rT1,
                                unsigned short* __restrict__ WT2, unsigned short* __restrict__ rT2) {
    __shared__ float t[64][65];
    int blk = blockIdx.x;
    const float* W; unsigned short* WT; int tr;
    if (blk < 256)      { W = w1 + (size_t)(blk >> 4) * DIM * DIM; WT = WT1 + (size_t)(blk >> 4) * DIM * DIM; tr = blk & 15; }
    else if (blk < 272) { W = r1; WT = rT1; tr = blk - 256; }
    else if (blk < 528) { int q = blk - 272; W = w2 + (size_t)(q >> 4) * DIM * DIM; WT = WT2 + (size_t)(q >> 4) * DIM * DIM; tr = q & 15; }
    else                { W = r2; WT = rT2; tr = blk - 528; }
    int tk = (tr >> 2) << 6;
    int to = (tr & 3) << 6;
    #pragma unroll
    for (int it = 0; it < 16; ++it) {
        int el = it * 256 + threadIdx.x;
        int row = el >> 6, col = el & 63;
        t[row][col] = W[(size_t)(tk + row) * DIM + to + col];
    }
    __syncthreads();
    #pragma unroll
    for (int it = 0; it < 16; ++it) {
        int el = it * 256 + threadIdx.x;
        int row = el >> 6, col = el & 63;
        WT[(size_t)(to + row) * DIM + tk + col] = f2bf(t[col][row]);
    }
}

// ---------------- fused: per-(tgt,rel) counts + per-block relation histogram ----------------
__global__ void k_hist2(const int* __restrict__ eidx, const int* __restrict__ etype,
                        unsigned int* __restrict__ cnt, int* __restrict__ bh) {
    __shared__ int h[NREL];
    int tid = threadIdx.x;
    if (tid < NREL) h[tid] = 0;
    __syncthreads();
    int e = blockIdx.x * 256 + tid;
    int rel = etype[e];
    int tgt = eidx[NEDGES + e];
    atomicAdd(&cnt[tgt * NREL + rel], 1u);
    atomicAdd(&h[rel], 1);
    __syncthreads();
    if (tid < NREL) bh[tid * NBLKS + blockIdx.x] = h[tid];
}

// ---------------- parallel scan: 16 waves, one per relation ----------------
__global__ void k_scan_par(int* __restrict__ bh, int* __restrict__ meta) {
    __shared__ int tot[NREL];
    __shared__ int base[NREL];
    int w = threadIdx.x >> 6, lane = threadIdx.x & 63;
    int vals[8];
    int run = 0;
    #pragma unroll
    for (int c = 0; c < 8; ++c) {
        int v = bh[w * NBLKS + c * 64 + lane];
        int s = v;
        #pragma unroll
        for (int off = 1; off < 64; off <<= 1) {
            int t = __shfl_up(s, off);
            if (lane >= off) s += t;
        }
        vals[c] = run + s - v;      // exclusive prefix within relation
        run += __shfl(s, 63);
    }
    if (lane == 0) tot[w] = run;
    __syncthreads();
    if (threadIdx.x == 0) {
        int s = 0;
        for (int r = 0; r < NREL; ++r) { base[r] = s; meta[16 + r] = s; s += (tot[r] + 63) & ~63; }
        meta[32] = s;
    }
    __syncthreads();
    int b = base[w];
    #pragma unroll
    for (int c = 0; c < 8; ++c) bh[w * NBLKS + c * 64 + lane] = vals[c] + b;
}

// ---------------- place edges into relation-sorted arrays (LDS cursors) ----------------
__global__ void k_place2(const int* __restrict__ eidx, const int* __restrict__ etype,
                         const int* __restrict__ bh, int* __restrict__ ssrc,
                         int* __restrict__ stgt) {
    __shared__ int cur[NREL];
    int tid = threadIdx.x;
    if (tid < NREL) cur[tid] = bh[tid * NBLKS + blockIdx.x];
    __syncthreads();
    int e = blockIdx.x * 256 + tid;
    int rel = etype[e];
    int pos = atomicAdd(&cur[rel], 1);
    ssrc[pos] = eidx[e];
    stgt[pos] = eidx[NEDGES + e];
}

// LDS tiles: unpadded, XOR-swizzled in 16B chunks (chunk ^= row&7). 40 KB total -> 4 blocks/CU.
#define AS_IDX(row, c16) ((row) * 64 + (((c16) ^ ((row) & 7)) << 3))

// ---------------- root GEMM: Y = bf16(X @ rootT^T + bias), plain stores ----------------
__launch_bounds__(256)
__global__ void k_gemm_root(const unsigned short* __restrict__ X, const unsigned short* __restrict__ BT,
                            const float* __restrict__ bias, unsigned short* __restrict__ Y) {
    __shared__ __align__(16) unsigned short As[64 * 64];
    __shared__ __align__(16) unsigned short Bs[256 * 64];
    int tid = threadIdx.x;
    int wave = tid >> 6, lane = tid & 63;
    int l16 = lane & 15, grp = lane >> 4;
    int bm = blockIdx.x;

    f32x4 acc[4][4];
    #pragma unroll
    for (int i = 0; i < 4; ++i)
        #pragma unroll
        for (int j = 0; j < 4; ++j) acc[i][j] = f32x4{0.f, 0.f, 0.f, 0.f};

    int arow = tid >> 3, ac16 = tid & 7;   // A stage: 8 threads/row, 2 iters
    for (int kt = 0; kt < 4; ++kt) {
        #pragma unroll
        for (int it = 0; it < 2; ++it) {
            int row = it * 32 + arow;
            u16x8 u = *(const u16x8*)&X[(size_t)(bm * 64 + row) * DIM + kt * 64 + ac16 * 8];
            *(u16x8*)&As[AS_IDX(row, ac16)] = u;
        }
        #pragma unroll
        for (int it = 0; it < 8; ++it) {
            int flat = it * 256 + tid;
            int row = flat >> 3, c16 = flat & 7;
            u16x8 u = *(const u16x8*)&BT[(size_t)row * DIM + kt * 64 + c16 * 8];
            *(u16x8*)&Bs[AS_IDX(row, c16)] = u;
        }
        __syncthreads();
        #pragma unroll
        for (int kk = 0; kk < 2; ++kk) {
            bf16x8 a[4], b[4];
            #pragma unroll
            for (int i = 0; i < 4; ++i) {
                int row = i * 16 + l16;
                a[i] = *(const bf16x8*)&As[AS_IDX(row, kk * 4 + grp)];
            }
            #pragma unroll
            for (int j = 0; j < 4; ++j) {
                int row = wave * 64 + j * 16 + l16;
                b[j] = *(const bf16x8*)&Bs[AS_IDX(row, kk * 4 + grp)];
            }
            #pragma unroll
            for (int i = 0; i < 4; ++i)
                #pragma unroll
                for (int j = 0; j < 4; ++j)
                    acc[i][j] = __builtin_amdgcn_mfma_f32_16x16x32_bf16(a[i], b[j], acc[i][j], 0, 0, 0);
        }
        __syncthreads();
    }
    #pragma unroll
    for (int i = 0; i < 4; ++i)
        #pragma unroll
        for (int reg = 0; reg < 4; ++reg) {
            int row = i * 16 + grp * 4 + reg;
            int gr = bm * 64 + row;
            #pragma unroll
            for (int j = 0; j < 4; ++j) {
                int col = wave * 64 + j * 16 + l16;
                float v = acc[i][j][reg] + bias[col];
                float vo = __shfl_xor(v, 1);
                if (!(lane & 1)) {
                    unsigned pk = (unsigned)f2bf(v) | ((unsigned)f2bf(vo) << 16);
                    *(unsigned*)&Y[(size_t)gr * DIM + col] = pk;
                }
            }
        }
}

// ---------------- edge GEMM: Y[tgt] += (x[src] @ W[rel]) * rcnt, pk-bf16 atomics ----------------
__launch_bounds__(256)
__global__ void k_gemm_edge(const unsigned short* __restrict__ X, const unsigned short* __restrict__ WT,
                            const int* __restrict__ ssrc, const int* __restrict__ stgt,
                            const unsigned int* __restrict__ cnt, const int* __restrict__ meta,
                            unsigned short* __restrict__ Y) {
    int base = blockIdx.x * 64;
    if (base >= meta[32]) return;
    int rel = 0;
    while (rel < 15 && meta[16 + rel + 1] <= base) ++rel;
    const unsigned short* BT = WT + (size_t)rel * DIM * DIM;

    __shared__ __align__(16) unsigned short As[64 * 64];
    __shared__ __align__(16) unsigned short Bs[256 * 64];
    int tid = threadIdx.x;
    int wave = tid >> 6, lane = tid & 63;
    int l16 = lane & 15, grp = lane >> 4;

    f32x4 acc[4][4];
    #pragma unroll
    for (int i = 0; i < 4; ++i)
        #pragma unroll
        for (int j = 0; j < 4; ++j) acc[i][j] = f32x4{0.f, 0.f, 0.f, 0.f};

    int arow = tid >> 3, ac16 = tid & 7;
    int s0 = ssrc[base + arow];
    int s1 = ssrc[base + 32 + arow];
    for (int kt = 0; kt < 4; ++kt) {
        #pragma unroll
        for (int it = 0; it < 2; ++it) {
            int row = it * 32 + arow;
            int s = it ? s1 : s0;
            u16x8 u = {};
            if (s >= 0) u = *(const u16x8*)&X[(size_t)s * DIM + kt * 64 + ac16 * 8];
            *(u16x8*)&As[AS_IDX(row, ac16)] = u;
        }
        #pragma unroll
        for (int it = 0; it < 8; ++it) {
            int flat = it * 256 + tid;
            int row = flat >> 3, c16 = flat & 7;
            u16x8 u = *(const u16x8*)&BT[(size_t)row * DIM + kt * 64 + c16 * 8];
            *(u16x8*)&Bs[AS_IDX(row, c16)] = u;
        }
        __syncthreads();
        #pragma unroll
        for (int kk = 0; kk < 2; ++kk) {
            bf16x8 a[4], b[4];
            #pragma unroll
            for (int i = 0; i < 4; ++i) {
                int row = i * 16 + l16;
                a[i] = *(const bf16x8*)&As[AS_IDX(row, kk * 4 + grp)];
            }
            #pragma unroll
            for (int j = 0; j < 4; ++j) {
                int row = wave * 64 + j * 16 + l16;
                b[j] = *(const bf16x8*)&Bs[AS_IDX(row, kk * 4 + grp)];
            }
            #pragma unroll
            for (int i = 0; i < 4; ++i)
                #pragma unroll
                for (int j = 0; j < 4; ++j)
                    acc[i][j] = __builtin_amdgcn_mfma_f32_16x16x32_bf16(a[i], b[j], acc[i][j], 0, 0, 0);
        }
        __syncthreads();
    }
    #pragma unroll
    for (int i = 0; i < 4; ++i)
        #pragma unroll
        for (int reg = 0; reg < 4; ++reg) {
            int row = i * 16 + grp * 4 + reg;
            int e = base + row;
            int s = ssrc[e];
            if (s < 0) continue;                 // uniform across the 16 lanes sharing this row
            int tgt = stgt[e];
            float rc = 1.0f / fmaxf((float)cnt[tgt * NREL + rel], 1.0f);
            unsigned short* Yrow = Y + (size_t)tgt * DIM;
            #pragma unroll
            for (int j = 0; j < 4; ++j) {
                int col = wave * 64 + j * 16 + l16;
                float v = acc[i][j][reg] * rc;
                float vo = __shfl_xor(v, 1);
                if (!(lane & 1)) {
                    __hip_bfloat162 hv;
                    ((unsigned short*)&hv)[0] = f2bf(v);
                    ((unsigned short*)&hv)[1] = f2bf(vo);
                    unsafeAtomicAdd((__hip_bfloat162*)(Yrow + col), hv);
                }
            }
        }
}

// ---------------- readout: out[q] += x2[i], run-compressed over sorted batch_ids ----------------
__global__ void k_readout(const unsigned short* __restrict__ X2, const int* __restrict__ bids,
                          float* __restrict__ out) {
    int gid = blockIdx.x * blockDim.x + threadIdx.x;  // 65536 threads
    int g = gid >> 5, c8 = gid & 31;                  // 8 nodes x 8 cols per thread
    int i0 = g * 8;
    float a[8];
    #pragma unroll
    for (int j = 0; j < 8; ++j) a[j] = 0.f;
    int curq = bids[i0];
    #pragma unroll
    for (int t = 0; t < 8; ++t) {
        int i = i0 + t;
        int q = bids[i];
        if (q != curq) {
            #pragma unroll
            for (int j = 0; j < 8; ++j) {
                unsafeAtomicAdd(&out[(size_t)curq * DIM + c8 * 8 + j], a[j]);
                a[j] = 0.f;
            }
            curq = q;
        }
        u16x8 v = *(const u16x8*)&X2[(size_t)i * DIM + c8 * 8];
        #pragma unroll
        for (int j = 0; j < 8; ++j) a[j] += bf2f(v[j]);
    }
    #pragma unroll
    for (int j = 0; j < 8; ++j)
        unsafeAtomicAdd(&out[(size_t)curq * DIM + c8 * 8 + j], a[j]);
}

extern "C" void kernel_launch(void* const* d_in, const int* in_sizes, int n_in,
                              void* d_out, int out_size, void* d_ws, size_t ws_size,
                              hipStream_t stream) {
    const float* emb   = (const float*)d_in[0];
    const float* w1    = (const float*)d_in[1];
    const float* root1 = (const float*)d_in[2];
    const float* b1    = (const float*)d_in[3];
    const float* w2    = (const float*)d_in[4];
    const float* root2 = (const float*)d_in[5];
    const float* b2    = (const float*)d_in[6];
    const int* eidx    = (const int*)d_in[7];
    const int* etype   = (const int*)d_in[8];
    const int* eids    = (const int*)d_in[9];
    const int* bids    = (const int*)d_in[10];
    float* out = (float*)d_out;

    char* ws = (char*)d_ws;
    unsigned short* x0  = (unsigned short*)(ws + (size_t)(0 << 20));   // 8 MB
    unsigned short* x1  = (unsigned short*)(ws + (size_t)(8 << 20));   // 8 MB
    unsigned short* x2  = (unsigned short*)(ws + (size_t)(16 << 20));  // 8 MB
    unsigned short* WT1 = (unsigned short*)(ws + (size_t)(24 << 20));  // 2 MB
    unsigned short* rT1 = (unsigned short*)(ws + (size_t)(26 << 20));  // 128 KB
    unsigned short* WT2 = (unsigned short*)(ws + (size_t)(27 << 20));  // 2 MB
    unsigned short* rT2 = (unsigned short*)(ws + (size_t)(29 << 20));  // 128 KB
    unsigned int*   cnt = (unsigned int*)(ws + (size_t)(30 << 20));    // 1 MB
    int*           meta = (int*)(ws + (size_t)(31 << 20));             // 256 B
    int*           ssrc = (int*)(ws + (size_t)(31 << 20) + 4096);      // 528 KB
    int*           stgt = (int*)(ws + (size_t)(32 << 20));             // 528 KB
    int*           bh   = (int*)(ws + (size_t)(33 << 20));             // 32 KB

    const int NBLK_EDGE = (NEDGES + NREL * 64) / 64;  // 2064

    hipMemsetAsync(cnt, 0, (size_t)NLOCAL * NREL * 4, stream);
    hipMemsetAsync(ssrc, 0xFF, (size_t)(NEDGES + NREL * 64) * 4, stream);
    hipMemsetAsync(out, 0, (size_t)NQ * DIM * 4, stream);

    k_gather<<<2048, 256, 0, stream>>>(emb, eids, x0);
    k_transpose_all<<<544, 256, 0, stream>>>(w1, root1, w2, root2, WT1, rT1, WT2, rT2);
    k_hist2<<<NBLKS, 256, 0, stream>>>(eidx, etype, cnt, bh);
    k_scan_par<<<1, 1024, 0, stream>>>(bh, meta);
    k_place2<<<NBLKS, 256, 0, stream>>>(eidx, etype, bh, ssrc, stgt);

    // layer 1
    k_gemm_root<<<NLOCAL / 64, 256, 0, stream>>>(x0, rT1, b1, x1);
    k_gemm_edge<<<NBLK_EDGE, 256, 0, stream>>>(x0, WT1, ssrc, stgt, cnt, meta, x1);
    // layer 2
    k_gemm_root<<<NLOCAL / 64, 256, 0, stream>>>(x1, rT2, b2, x2);
    k_gemm_edge<<<NBLK_EDGE, 256, 0, stream>>>(x1, WT2, ssrc, stgt, cnt, meta, x2);

    k_readout<<<256, 256, 0, stream>>>(x2, bids, out);
}

// Round 5
// 470.190 us; speedup vs baseline: 2.0417x; 1.0753x over previous
//
#include <hip/hip_runtime.h>
#include <hip/hip_bf16.h>

#define NLOCAL 16384
#define NEDGES 131072
#define NREL   16
#define DIM    256
#define NQ     4096
#define NBLKS  512            // NEDGES / 256
#define NSLOTS (NEDGES + NREL * 64)   // 132096 padded slots

typedef __bf16 bf16x8 __attribute__((ext_vector_type(8)));
typedef float  f32x4  __attribute__((ext_vector_type(4)));
typedef unsigned short u16x4 __attribute__((ext_vector_type(4)));
typedef unsigned short u16x8 __attribute__((ext_vector_type(8)));

static __device__ __forceinline__ unsigned short f2bf(float f) {
    union { float f; unsigned u; } v; v.f = f;
    unsigned r = v.u + 0x7FFFu + ((v.u >> 16) & 1u);
    return (unsigned short)(r >> 16);
}
static __device__ __forceinline__ float bf2f(unsigned short s) {
    union { unsigned u; float f; } v; v.u = ((unsigned)s) << 16;
    return v.f;
}

// ---------------- gather x0 = bf16(emb[entity_ids]) ----------------
__global__ void k_gather(const float* __restrict__ emb, const int* __restrict__ ids,
                         unsigned short* __restrict__ x0) {
    int gid = blockIdx.x * blockDim.x + threadIdx.x;   // 16384*32 threads
    int i = gid >> 5, c8 = gid & 31;
    int e = ids[i];
    const f32x4* src = (const f32x4*)(emb + (size_t)e * DIM + c8 * 8);
    f32x4 a = src[0], b = src[1];
    u16x8 u;
    u[0] = f2bf(a[0]); u[1] = f2bf(a[1]); u[2] = f2bf(a[2]); u[3] = f2bf(a[3]);
    u[4] = f2bf(b[0]); u[5] = f2bf(b[1]); u[6] = f2bf(b[2]); u[7] = f2bf(b[3]);
    *(u16x8*)&x0[(size_t)i * DIM + c8 * 8] = u;
}

// ---------------- transpose+bf16 all weights in one launch ----------------
__global__ void k_transpose_all(const float* __restrict__ w1, const float* __restrict__ r1,
                                const float* __restrict__ w2, const float* __restrict__ r2,
                                unsigned short* __restrict__ WT1, unsigned short* __restrict__ rT1,
                                unsigned short* __restrict__ WT2, unsigned short* __restrict__ rT2) {
    __shared__ float t[64][65];
    int blk = blockIdx.x;
    const float* W; unsigned short* WT; int tr;
    if (blk < 256)      { W = w1 + (size_t)(blk >> 4) * DIM * DIM; WT = WT1 + (size_t)(blk >> 4) * DIM * DIM; tr = blk & 15; }
    else if (blk < 272) { W = r1; WT = rT1; tr = blk - 256; }
    else if (blk < 528) { int q = blk - 272; W = w2 + (size_t)(q >> 4) * DIM * DIM; WT = WT2 + (size_t)(q >> 4) * DIM * DIM; tr = q & 15; }
    else                { W = r2; WT = rT2; tr = blk - 528; }
    int tk = (tr >> 2) << 6;
    int to = (tr & 3) << 6;
    #pragma unroll
    for (int it = 0; it < 16; ++it) {
        int el = it * 256 + threadIdx.x;
        int row = el >> 6, col = el & 63;
        t[row][col] = W[(size_t)(tk + row) * DIM + to + col];
    }
    __syncthreads();
    #pragma unroll
    for (int it = 0; it < 16; ++it) {
        int el = it * 256 + threadIdx.x;
        int row = el >> 6, col = el & 63;
        WT[(size_t)(to + row) * DIM + tk + col] = f2bf(t[col][row]);
    }
}

// ---------------- fused: bucket counts + per-tgt counts + per-block relation histogram ----------------
__global__ void k_hist2(const int* __restrict__ eidx, const int* __restrict__ etype,
                        unsigned int* __restrict__ cnt, unsigned int* __restrict__ cnt_t,
                        int* __restrict__ bh) {
    __shared__ int h[NREL];
    int tid = threadIdx.x;
    if (tid < NREL) h[tid] = 0;
    __syncthreads();
    int e = blockIdx.x * 256 + tid;
    int rel = etype[e];
    int tgt = eidx[NEDGES + e];
    atomicAdd(&cnt[tgt * NREL + rel], 1u);
    atomicAdd(&cnt_t[tgt], 1u);
    atomicAdd(&h[rel], 1);
    __syncthreads();
    if (tid < NREL) bh[tid * NBLKS + blockIdx.x] = h[tid];
}

// ---------------- parallel scan over relation-block histogram ----------------
__global__ void k_scan_par(int* __restrict__ bh, int* __restrict__ meta) {
    __shared__ int tot[NREL];
    __shared__ int base[NREL];
    int w = threadIdx.x >> 6, lane = threadIdx.x & 63;
    int vals[8];
    int run = 0;
    #pragma unroll
    for (int c = 0; c < 8; ++c) {
        int v = bh[w * NBLKS + c * 64 + lane];
        int s = v;
        #pragma unroll
        for (int off = 1; off < 64; off <<= 1) {
            int t = __shfl_up(s, off);
            if (lane >= off) s += t;
        }
        vals[c] = run + s - v;
        run += __shfl(s, 63);
    }
    if (lane == 0) tot[w] = run;
    __syncthreads();
    if (threadIdx.x == 0) {
        int s = 0;
        for (int r = 0; r < NREL; ++r) { base[r] = s; meta[16 + r] = s; s += (tot[r] + 63) & ~63; }
        meta[32] = s;
    }
    __syncthreads();
    int b = base[w];
    #pragma unroll
    for (int c = 0; c < 8; ++c) bh[w * NBLKS + c * 64 + lane] = vals[c] + b;
}

// ---------------- place edges into relation-sorted arrays (LDS cursors) ----------------
__global__ void k_place2(const int* __restrict__ eidx, const int* __restrict__ etype,
                         const int* __restrict__ bh, int* __restrict__ ssrc,
                         int* __restrict__ stgt) {
    __shared__ int cur[NREL];
    int tid = threadIdx.x;
    if (tid < NREL) cur[tid] = bh[tid * NBLKS + blockIdx.x];
    __syncthreads();
    int e = blockIdx.x * 256 + tid;
    int rel = etype[e];
    int pos = atomicAdd(&cur[rel], 1);
    ssrc[pos] = eidx[e];
    stgt[pos] = eidx[NEDGES + e];
}

// ---------------- scan over per-tgt counts -> CSR row_ptr + cursors ----------------
__global__ void k_scan_t(const unsigned int* __restrict__ cnt_t, int* __restrict__ row_ptr,
                         int* __restrict__ cur) {
    __shared__ int wsum[16];
    int tid = threadIdx.x;              // 1024 threads, 16 bins each
    int wave = tid >> 6, lane = tid & 63;
    int base = tid * 16;
    int loc[16];
    int s = 0;
    #pragma unroll
    for (int c = 0; c < 16; ++c) { loc[c] = s; s += (int)cnt_t[base + c]; }
    int inc = s;
    #pragma unroll
    for (int off = 1; off < 64; off <<= 1) {
        int t = __shfl_up(inc, off);
        if (lane >= off) inc += t;
    }
    if (lane == 63) wsum[wave] = inc;
    __syncthreads();
    if (tid == 0) {
        int a = 0;
        for (int w = 0; w < 16; ++w) { int v = wsum[w]; wsum[w] = a; a += v; }
    }
    __syncthreads();
    int excl = wsum[wave] + inc - s;
    #pragma unroll
    for (int c = 0; c < 16; ++c) { int v = excl + loc[c]; row_ptr[base + c] = v; cur[base + c] = v; }
    if (tid == 1023) row_ptr[NLOCAL] = excl + s;
}

// ---------------- place slot indices into tgt-CSR ----------------
__global__ void k_place_t(const int* __restrict__ ssrc, const int* __restrict__ stgt,
                          int* __restrict__ cur, int* __restrict__ elist) {
    int p = blockIdx.x * 256 + threadIdx.x;   // over NSLOTS
    int s = ssrc[p];
    if (s >= 0) {
        int tgt = stgt[p];
        int pos = atomicAdd(&cur[tgt], 1);
        elist[pos] = p;
    }
}

// LDS A tile: unpadded, XOR-swizzled in 16B chunks (chunk ^= row&7).
#define AS_IDX(row, c16) ((row) * 64 + (((c16) ^ ((row) & 7)) << 3))

// ---------------- root GEMM: rootY = bf16(X @ rootT^T + bias); B direct from L2 ----------------
__launch_bounds__(256)
__global__ void k_gemm_root(const unsigned short* __restrict__ X, const unsigned short* __restrict__ BT,
                            const float* __restrict__ bias, unsigned short* __restrict__ Y) {
    __shared__ __align__(16) unsigned short As[2][64 * 64];
    int tid = threadIdx.x;
    int wave = tid >> 6, lane = tid & 63;
    int l16 = lane & 15, grp = lane >> 4;
    int bm = blockIdx.x;
    int arow = tid >> 3, ac16 = tid & 7;

    f32x4 acc[4][4];
    #pragma unroll
    for (int i = 0; i < 4; ++i)
        #pragma unroll
        for (int j = 0; j < 4; ++j) acc[i][j] = f32x4{0.f, 0.f, 0.f, 0.f};

    // prologue stage kt=0
    #pragma unroll
    for (int it = 0; it < 2; ++it) {
        int row = it * 32 + arow;
        u16x8 u = *(const u16x8*)&X[(size_t)(bm * 64 + row) * DIM + ac16 * 8];
        *(u16x8*)&As[0][AS_IDX(row, ac16)] = u;
    }
    for (int kt = 0; kt < 4; ++kt) {
        __syncthreads();
        if (kt < 3) {
            #pragma unroll
            for (int it = 0; it < 2; ++it) {
                int row = it * 32 + arow;
                u16x8 u = *(const u16x8*)&X[(size_t)(bm * 64 + row) * DIM + (kt + 1) * 64 + ac16 * 8];
                *(u16x8*)&As[(kt + 1) & 1][AS_IDX(row, ac16)] = u;
            }
        }
        const unsigned short* buf = As[kt & 1];
        #pragma unroll
        for (int kk = 0; kk < 2; ++kk) {
            bf16x8 a[4], b[4];
            #pragma unroll
            for (int i = 0; i < 4; ++i)
                a[i] = *(const bf16x8*)&buf[AS_IDX(i * 16 + l16, kk * 4 + grp)];
            #pragma unroll
            for (int j = 0; j < 4; ++j)
                b[j] = *(const bf16x8*)&BT[(size_t)(wave * 64 + j * 16 + l16) * DIM + kt * 64 + kk * 32 + grp * 8];
            #pragma unroll
            for (int i = 0; i < 4; ++i)
                #pragma unroll
                for (int j = 0; j < 4; ++j)
                    acc[i][j] = __builtin_amdgcn_mfma_f32_16x16x32_bf16(a[i], b[j], acc[i][j], 0, 0, 0);
        }
    }
    #pragma unroll
    for (int i = 0; i < 4; ++i)
        #pragma unroll
        for (int reg = 0; reg < 4; ++reg) {
            int row = i * 16 + grp * 4 + reg;
            int gr = bm * 64 + row;
            #pragma unroll
            for (int j = 0; j < 4; ++j) {
                int col = wave * 64 + j * 16 + l16;
                float v = acc[i][j][reg] + bias[col];
                float vo = __shfl_xor(v, 1);
                if (!(lane & 1)) {
                    unsigned pk = (unsigned)f2bf(v) | ((unsigned)f2bf(vo) << 16);
                    *(unsigned*)&Y[(size_t)gr * DIM + col] = pk;
                }
            }
        }
}

// ---------------- edge GEMM: ye[e] = (x[src[e]] @ W[rel]) * rc, PLAIN stores ----------------
__launch_bounds__(256)
__global__ void k_gemm_edge(const unsigned short* __restrict__ X, const unsigned short* __restrict__ WT,
                            const int* __restrict__ ssrc, const int* __restrict__ stgt,
                            const unsigned int* __restrict__ cnt, const int* __restrict__ meta,
                            unsigned short* __restrict__ ye) {
    int base = blockIdx.x * 64;
    if (base >= meta[32]) return;
    int rel = 0;
    while (rel < 15 && meta[16 + rel + 1] <= base) ++rel;
    const unsigned short* BT = WT + (size_t)rel * DIM * DIM;

    __shared__ __align__(16) unsigned short As[2][64 * 64];
    int tid = threadIdx.x;
    int wave = tid >> 6, lane = tid & 63;
    int l16 = lane & 15, grp = lane >> 4;
    int arow = tid >> 3, ac16 = tid & 7;

    f32x4 acc[4][4];
    #pragma unroll
    for (int i = 0; i < 4; ++i)
        #pragma unroll
        for (int j = 0; j < 4; ++j) acc[i][j] = f32x4{0.f, 0.f, 0.f, 0.f};

    int s0 = ssrc[base + arow];
    int s1 = ssrc[base + 32 + arow];
    // prologue stage kt=0
    #pragma unroll
    for (int it = 0; it < 2; ++it) {
        int row = it * 32 + arow;
        int s = it ? s1 : s0;
        u16x8 u = {};
        if (s >= 0) u = *(const u16x8*)&X[(size_t)s * DIM + ac16 * 8];
        *(u16x8*)&As[0][AS_IDX(row, ac16)] = u;
    }
    for (int kt = 0; kt < 4; ++kt) {
        __syncthreads();
        if (kt < 3) {
            #pragma unroll
            for (int it = 0; it < 2; ++it) {
                int row = it * 32 + arow;
                int s = it ? s1 : s0;
                u16x8 u = {};
                if (s >= 0) u = *(const u16x8*)&X[(size_t)s * DIM + (kt + 1) * 64 + ac16 * 8];
                *(u16x8*)&As[(kt + 1) & 1][AS_IDX(row, ac16)] = u;
            }
        }
        const unsigned short* buf = As[kt & 1];
        #pragma unroll
        for (int kk = 0; kk < 2; ++kk) {
            bf16x8 a[4], b[4];
            #pragma unroll
            for (int i = 0; i < 4; ++i)
                a[i] = *(const bf16x8*)&buf[AS_IDX(i * 16 + l16, kk * 4 + grp)];
            #pragma unroll
            for (int j = 0; j < 4; ++j)
                b[j] = *(const bf16x8*)&BT[(size_t)(wave * 64 + j * 16 + l16) * DIM + kt * 64 + kk * 32 + grp * 8];
            #pragma unroll
            for (int i = 0; i < 4; ++i)
                #pragma unroll
                for (int j = 0; j < 4; ++j)
                    acc[i][j] = __builtin_amdgcn_mfma_f32_16x16x32_bf16(a[i], b[j], acc[i][j], 0, 0, 0);
        }
    }
    #pragma unroll
    for (int i = 0; i < 4; ++i)
        #pragma unroll
        for (int reg = 0; reg < 4; ++reg) {
            int row = i * 16 + grp * 4 + reg;
            int e = base + row;
            int s = ssrc[e];
            int tgt = stgt[e];
            float rc = (s >= 0) ? 1.0f / fmaxf((float)cnt[tgt * NREL + rel], 1.0f) : 0.0f;
            #pragma unroll
            for (int j = 0; j < 4; ++j) {
                int col = wave * 64 + j * 16 + l16;
                float v = acc[i][j][reg] * rc;
                float vo = __shfl_xor(v, 1);
                if (s >= 0 && !(lane & 1)) {
                    unsigned pk = (unsigned)f2bf(v) | ((unsigned)f2bf(vo) << 16);
                    *(unsigned*)&ye[(size_t)e * DIM + col] = pk;
                }
            }
        }
}

// ---------------- combine: x_out[t] = rootY[t] + sum_{p in CSR[t]} ye[p] (fp32 accum) ----------------
__global__ void k_combine(const unsigned short* __restrict__ rootY, const unsigned short* __restrict__ ye,
                          const int* __restrict__ row_ptr, const int* __restrict__ elist,
                          unsigned short* __restrict__ Xout) {
    int wave = threadIdx.x >> 6, lane = threadIdx.x & 63;
    int tgt = blockIdx.x * 4 + wave;
    int c0 = lane * 4;
    u16x4 rv = *(const u16x4*)&rootY[(size_t)tgt * DIM + c0];
    float a0 = bf2f(rv[0]), a1 = bf2f(rv[1]), a2 = bf2f(rv[2]), a3 = bf2f(rv[3]);
    int p0 = row_ptr[tgt], p1 = row_ptr[tgt + 1];
    for (int p = p0; p < p1; ++p) {
        int idx = elist[p];
        u16x4 v = *(const u16x4*)&ye[(size_t)idx * DIM + c0];
        a0 += bf2f(v[0]); a1 += bf2f(v[1]); a2 += bf2f(v[2]); a3 += bf2f(v[3]);
    }
    u16x4 o;
    o[0] = f2bf(a0); o[1] = f2bf(a1); o[2] = f2bf(a2); o[3] = f2bf(a3);
    *(u16x4*)&Xout[(size_t)tgt * DIM + c0] = o;
}

// ---------------- readout: out[q] += x2[i], run-compressed over sorted batch_ids ----------------
__global__ void k_readout(const unsigned short* __restrict__ X2, const int* __restrict__ bids,
                          float* __restrict__ out) {
    int gid = blockIdx.x * blockDim.x + threadIdx.x;  // 65536 threads
    int g = gid >> 5, c8 = gid & 31;
    int i0 = g * 8;
    float a[8];
    #pragma unroll
    for (int j = 0; j < 8; ++j) a[j] = 0.f;
    int curq = bids[i0];
    #pragma unroll
    for (int t = 0; t < 8; ++t) {
        int i = i0 + t;
        int q = bids[i];
        if (q != curq) {
            #pragma unroll
            for (int j = 0; j < 8; ++j) {
                unsafeAtomicAdd(&out[(size_t)curq * DIM + c8 * 8 + j], a[j]);
                a[j] = 0.f;
            }
            curq = q;
        }
        u16x8 v = *(const u16x8*)&X2[(size_t)i * DIM + c8 * 8];
        #pragma unroll
        for (int j = 0; j < 8; ++j) a[j] += bf2f(v[j]);
    }
    #pragma unroll
    for (int j = 0; j < 8; ++j)
        unsafeAtomicAdd(&out[(size_t)curq * DIM + c8 * 8 + j], a[j]);
}

extern "C" void kernel_launch(void* const* d_in, const int* in_sizes, int n_in,
                              void* d_out, int out_size, void* d_ws, size_t ws_size,
                              hipStream_t stream) {
    const float* emb   = (const float*)d_in[0];
    const float* w1    = (const float*)d_in[1];
    const float* root1 = (const float*)d_in[2];
    const float* b1    = (const float*)d_in[3];
    const float* w2    = (const float*)d_in[4];
    const float* root2 = (const float*)d_in[5];
    const float* b2    = (const float*)d_in[6];
    const int* eidx    = (const int*)d_in[7];
    const int* etype   = (const int*)d_in[8];
    const int* eids    = (const int*)d_in[9];
    const int* bids    = (const int*)d_in[10];
    float* out = (float*)d_out;

    char* ws = (char*)d_ws;
    unsigned short* x0   = (unsigned short*)(ws + (size_t)(0 << 20));   // 8 MB
    unsigned short* x1   = (unsigned short*)(ws + (size_t)(8 << 20));   // 8 MB
    unsigned short* x2   = (unsigned short*)(ws + (size_t)(16 << 20));  // 8 MB
    unsigned short* WT1  = (unsigned short*)(ws + (size_t)(24 << 20));  // 2 MB
    unsigned short* rT1  = (unsigned short*)(ws + (size_t)(26 << 20));  // 128 KB
    unsigned short* WT2  = (unsigned short*)(ws + (size_t)(27 << 20));  // 2 MB
    unsigned short* rT2  = (unsigned short*)(ws + (size_t)(29 << 20));  // 128 KB
    unsigned int*   cnt  = (unsigned int*)(ws + (size_t)(30 << 20));    // 1 MB
    int*           meta  = (int*)(ws + (size_t)(31 << 20));             // 256 B
    int*           ssrc  = (int*)(ws + (size_t)(31 << 20) + 4096);      // 528 KB
    int*           stgt  = (int*)(ws + (size_t)(32 << 20));             // 528 KB
    int*           bh    = (int*)(ws + (size_t)(33 << 20));             // 32 KB
    unsigned int*  cnt_t = (unsigned int*)(ws + (size_t)(33 << 20) + 65536);   // 64 KB
    int*         row_ptr = (int*)(ws + (size_t)(33 << 20) + 2 * 65536);        // 64 KB + 4
    int*           cur_t = (int*)(ws + (size_t)(33 << 20) + 3 * 65536 + 4096); // 64 KB
    int*           elist = (int*)(ws + (size_t)(34 << 20));             // 512 KB
    unsigned short* rootY= (unsigned short*)(ws + (size_t)(35 << 20));  // 8 MB
    unsigned short* ye   = (unsigned short*)(ws + (size_t)(43 << 20));  // 67.6 MB

    const int NBLK_EDGE = NSLOTS / 64;  // 2064

    hipMemsetAsync(cnt, 0, (size_t)NLOCAL * NREL * 4, stream);
    hipMemsetAsync(cnt_t, 0, (size_t)NLOCAL * 4, stream);
    hipMemsetAsync(ssrc, 0xFF, (size_t)NSLOTS * 4, stream);
    hipMemsetAsync(out, 0, (size_t)NQ * DIM * 4, stream);

    k_gather<<<2048, 256, 0, stream>>>(emb, eids, x0);
    k_transpose_all<<<544, 256, 0, stream>>>(w1, root1, w2, root2, WT1, rT1, WT2, rT2);
    k_hist2<<<NBLKS, 256, 0, stream>>>(eidx, etype, cnt, cnt_t, bh);
    k_scan_par<<<1, 1024, 0, stream>>>(bh, meta);
    k_place2<<<NBLKS, 256, 0, stream>>>(eidx, etype, bh, ssrc, stgt);
    k_scan_t<<<1, 1024, 0, stream>>>(cnt_t, row_ptr, cur_t);
    k_place_t<<<NSLOTS / 256, 256, 0, stream>>>(ssrc, stgt, cur_t, elist);

    // layer 1
    k_gemm_root<<<NLOCAL / 64, 256, 0, stream>>>(x0, rT1, b1, rootY);
    k_gemm_edge<<<NBLK_EDGE, 256, 0, stream>>>(x0, WT1, ssrc, stgt, cnt, meta, ye);
    k_combine<<<NLOCAL / 4, 256, 0, stream>>>(rootY, ye, row_ptr, elist, x1);
    // layer 2
    k_gemm_root<<<NLOCAL / 64, 256, 0, stream>>>(x1, rT2, b2, rootY);
    k_gemm_edge<<<NBLK_EDGE, 256, 0, stream>>>(x1, WT2, ssrc, stgt, cnt, meta, ye);
    k_combine<<<NLOCAL / 4, 256, 0, stream>>>(rootY, ye, row_ptr, elist, x2);

    k_readout<<<256, 256, 0, stream>>>(x2, bids, out);
}

// Round 8
// 467.986 us; speedup vs baseline: 2.0513x; 1.0047x over previous
//
#include <hip/hip_runtime.h>
#include <hip/hip_bf16.h>

#define NLOCAL 16384
#define NEDGES 131072
#define NREL   16
#define DIM    256
#define NQ     4096
#define NBLKS  512                    // NEDGES / 256
#define NSLOTS (NEDGES + NREL * 64)   // 132096 padded slots
#define NBLKE  (NSLOTS / 64)          // 2064 edge-GEMM blocks

typedef __bf16 bf16x8 __attribute__((ext_vector_type(8)));
typedef float  f32x4  __attribute__((ext_vector_type(4)));
typedef unsigned short u16x4 __attribute__((ext_vector_type(4)));
typedef unsigned short u16x8 __attribute__((ext_vector_type(8)));

static __device__ __forceinline__ unsigned short f2bf(float f) {
    union { float f; unsigned u; } v; v.f = f;
    unsigned r = v.u + 0x7FFFu + ((v.u >> 16) & 1u);
    return (unsigned short)(r >> 16);
}
static __device__ __forceinline__ float bf2f(unsigned short s) {
    union { unsigned u; float f; } v; v.u = ((unsigned)s) << 16;
    return v.f;
}

// ---------------- gather x0 = bf16(emb[entity_ids]) ----------------
__global__ void k_gather(const float* __restrict__ emb, const int* __restrict__ ids,
                         unsigned short* __restrict__ x0) {
    int gid = blockIdx.x * blockDim.x + threadIdx.x;   // 16384*32 threads
    int i = gid >> 5, c8 = gid & 31;
    int e = ids[i];
    const f32x4* src = (const f32x4*)(emb + (size_t)e * DIM + c8 * 8);
    f32x4 a = src[0], b = src[1];
    u16x8 u;
    u[0] = f2bf(a[0]); u[1] = f2bf(a[1]); u[2] = f2bf(a[2]); u[3] = f2bf(a[3]);
    u[4] = f2bf(b[0]); u[5] = f2bf(b[1]); u[6] = f2bf(b[2]); u[7] = f2bf(b[3]);
    *(u16x8*)&x0[(size_t)i * DIM + c8 * 8] = u;
}

// ---------------- transpose+bf16 all weights in one launch ----------------
__global__ void k_transpose_all(const float* __restrict__ w1, const float* __restrict__ r1,
                                const float* __restrict__ w2, const float* __restrict__ r2,
                                unsigned short* __restrict__ WT1, unsigned short* __restrict__ rT1,
                                unsigned short* __restrict__ WT2, unsigned short* __restrict__ rT2) {
    __shared__ float t[64][65];
    int blk = blockIdx.x;
    const float* W; unsigned short* WT; int tr;
    if (blk < 256)      { W = w1 + (size_t)(blk >> 4) * DIM * DIM; WT = WT1 + (size_t)(blk >> 4) * DIM * DIM; tr = blk & 15; }
    else if (blk < 272) { W = r1; WT = rT1; tr = blk - 256; }
    else if (blk < 528) { int q = blk - 272; W = w2 + (size_t)(q >> 4) * DIM * DIM; WT = WT2 + (size_t)(q >> 4) * DIM * DIM; tr = q & 15; }
    else                { W = r2; WT = rT2; tr = blk - 528; }
    int tk = (tr >> 2) << 6;
    int to = (tr & 3) << 6;
    #pragma unroll
    for (int it = 0; it < 16; ++it) {
        int el = it * 256 + threadIdx.x;
        int row = el >> 6, col = el & 63;
        t[row][col] = W[(size_t)(tk + row) * DIM + to + col];
    }
    __syncthreads();
    #pragma unroll
    for (int it = 0; it < 16; ++it) {
        int el = it * 256 + threadIdx.x;
        int row = el >> 6, col = el & 63;
        WT[(size_t)(to + row) * DIM + tk + col] = f2bf(t[col][row]);
    }
}

// ---------------- fused: bucket counts + per-tgt counts + per-block relation histogram ----------------
__global__ void k_hist2(const int* __restrict__ eidx, const int* __restrict__ etype,
                        unsigned int* __restrict__ cnt, unsigned int* __restrict__ cnt_t,
                        int* __restrict__ bh) {
    __shared__ int h[NREL];
    int tid = threadIdx.x;
    if (tid < NREL) h[tid] = 0;
    __syncthreads();
    int e = blockIdx.x * 256 + tid;
    int rel = etype[e];
    int tgt = eidx[NEDGES + e];
    atomicAdd(&cnt[tgt * NREL + rel], 1u);
    atomicAdd(&cnt_t[tgt], 1u);
    atomicAdd(&h[rel], 1);
    __syncthreads();
    if (tid < NREL) bh[tid * NBLKS + blockIdx.x] = h[tid];
}

// ---------------- one kernel: rel-block scan + region bases + blk->rel LUT + tgt CSR scan ----------------
__global__ void k_scan_all(int* __restrict__ bh, int* __restrict__ meta,
                           const unsigned int* __restrict__ cnt_t, int* __restrict__ row_ptr,
                           int* __restrict__ cur_t, int* __restrict__ blk_rel) {
    __shared__ int tot[NREL];
    __shared__ int rs[NREL + 1];
    __shared__ int wsum[16];
    int tid = threadIdx.x;             // 1024 threads
    int w = tid >> 6, lane = tid & 63;

    // --- phase A: per-relation exclusive scan over 512 blocks ---
    int vals[8];
    int run = 0;
    #pragma unroll
    for (int c = 0; c < 8; ++c) {
        int v = bh[w * NBLKS + c * 64 + lane];
        int s = v;
        #pragma unroll
        for (int off = 1; off < 64; off <<= 1) {
            int t = __shfl_up(s, off);
            if (lane >= off) s += t;
        }
        vals[c] = run + s - v;
        run += __shfl(s, 63);
    }
    if (lane == 0) tot[w] = run;
    __syncthreads();
    if (tid == 0) {
        int s = 0;
        for (int r = 0; r < NREL; ++r) { rs[r] = s; meta[16 + r] = s; s += (tot[r] + 63) & ~63; }
        rs[NREL] = s; meta[32] = s;
    }
    __syncthreads();
    int b0 = rs[w];
    #pragma unroll
    for (int c = 0; c < 8; ++c) bh[w * NBLKS + c * 64 + lane] = vals[c] + b0;

    // --- phase B: blk -> rel LUT ---
    int total = rs[NREL];
    for (int b = tid; b < NBLKE; b += 1024) {
        int base = b * 64;
        int r;
        if (base >= total) r = -1;
        else { r = 0; while (r < 15 && rs[r + 1] <= base) ++r; }
        blk_rel[b] = r;
    }

    // --- phase C: tgt CSR scan (16 bins per thread) ---
    int base16 = tid * 16;
    int loc[16];
    int s = 0;
    #pragma unroll
    for (int c = 0; c < 16; ++c) { loc[c] = s; s += (int)cnt_t[base16 + c]; }
    int inc = s;
    #pragma unroll
    for (int off = 1; off < 64; off <<= 1) {
        int t = __shfl_up(inc, off);
        if (lane >= off) inc += t;
    }
    if (lane == 63) wsum[w] = inc;
    __syncthreads();
    if (tid == 0) {
        int a = 0;
        for (int q = 0; q < 16; ++q) { int v = wsum[q]; wsum[q] = a; a += v; }
    }
    __syncthreads();
    int excl = wsum[w] + inc - s;
    #pragma unroll
    for (int c = 0; c < 16; ++c) { int v = excl + loc[c]; row_ptr[base16 + c] = v; cur_t[base16 + c] = v; }
    if (tid == 1023) row_ptr[NLOCAL] = excl + s;
}

// ---------------- place edges (rel-sorted) + tgt-CSR fill, one pass ----------------
__global__ void k_place2(const int* __restrict__ eidx, const int* __restrict__ etype,
                         const int* __restrict__ bh, int* __restrict__ ssrc,
                         int* __restrict__ stgt, int* __restrict__ cur_t,
                         int* __restrict__ elist) {
    __shared__ int cur[NREL];
    int tid = threadIdx.x;
    if (tid < NREL) cur[tid] = bh[tid * NBLKS + blockIdx.x];
    __syncthreads();
    int e = blockIdx.x * 256 + tid;
    int rel = etype[e];
    int tgt = eidx[NEDGES + e];
    int pos = atomicAdd(&cur[rel], 1);
    ssrc[pos] = eidx[e];
    stgt[pos] = tgt;
    int q = atomicAdd(&cur_t[tgt], 1);
    elist[q] = pos;
}

// LDS A tile: unpadded, XOR-swizzled in 16B chunks (chunk ^= row&7).
#define AS_IDX(row, c16) ((row) * 64 + (((c16) ^ ((row) & 7)) << 3))

// ---------------- root GEMM: rootY = bf16(X @ rootT^T + bias); coalesced epilogue ----------------
__launch_bounds__(256)
__global__ void k_gemm_root(const unsigned short* __restrict__ X, const unsigned short* __restrict__ BT,
                            const float* __restrict__ bias, unsigned short* __restrict__ Y) {
    __shared__ __align__(16) unsigned short smem[16384];   // 32 KB: dbuf A tiles + output tile
    unsigned short* As0 = smem;
    unsigned short* As1 = smem + 4096;
    int tid = threadIdx.x;
    int wave = tid >> 6, lane = tid & 63;
    int l16 = lane & 15, grp = lane >> 4;
    int bm = blockIdx.x;
    int arow = tid >> 3, ac16 = tid & 7;

    f32x4 acc[4][4];
    #pragma unroll
    for (int i = 0; i < 4; ++i)
        #pragma unroll
        for (int j = 0; j < 4; ++j) acc[i][j] = f32x4{0.f, 0.f, 0.f, 0.f};

    #pragma unroll
    for (int it = 0; it < 2; ++it) {
        int row = it * 32 + arow;
        u16x8 u = *(const u16x8*)&X[(size_t)(bm * 64 + row) * DIM + ac16 * 8];
        *(u16x8*)&As0[AS_IDX(row, ac16)] = u;
    }
    for (int kt = 0; kt < 4; ++kt) {
        __syncthreads();
        if (kt < 3) {
            unsigned short* dst = (kt & 1) ? As0 : As1;
            #pragma unroll
            for (int it = 0; it < 2; ++it) {
                int row = it * 32 + arow;
                u16x8 u = *(const u16x8*)&X[(size_t)(bm * 64 + row) * DIM + (kt + 1) * 64 + ac16 * 8];
                *(u16x8*)&dst[AS_IDX(row, ac16)] = u;
            }
        }
        const unsigned short* buf = (kt & 1) ? As1 : As0;
        bf16x8 b[2][4];
        #pragma unroll
        for (int kk = 0; kk < 2; ++kk)
            #pragma unroll
            for (int j = 0; j < 4; ++j)
                b[kk][j] = *(const bf16x8*)&BT[(size_t)(wave * 64 + j * 16 + l16) * DIM + kt * 64 + kk * 32 + grp * 8];
        #pragma unroll
        for (int kk = 0; kk < 2; ++kk) {
            bf16x8 a[4];
            #pragma unroll
            for (int i = 0; i < 4; ++i)
                a[i] = *(const bf16x8*)&buf[AS_IDX(i * 16 + l16, kk * 4 + grp)];
            #pragma unroll
            for (int i = 0; i < 4; ++i)
                #pragma unroll
                for (int j = 0; j < 4; ++j)
                    acc[i][j] = __builtin_amdgcn_mfma_f32_16x16x32_bf16(a[i], b[kk][j], acc[i][j], 0, 0, 0);
        }
    }
    __syncthreads();
    // stage to LDS output tile (bf16, pair-packed)
    #pragma unroll
    for (int i = 0; i < 4; ++i)
        #pragma unroll
        for (int reg = 0; reg < 4; ++reg) {
            int row = i * 16 + grp * 4 + reg;
            #pragma unroll
            for (int j = 0; j < 4; ++j) {
                int col = wave * 64 + j * 16 + l16;
                float v = acc[i][j][reg] + bias[col];
                float vo = __shfl_xor(v, 1);
                if (!(lane & 1)) {
                    unsigned pk = (unsigned)f2bf(v) | ((unsigned)f2bf(vo) << 16);
                    *(unsigned*)&smem[row * 256 + col] = pk;
                }
            }
        }
    __syncthreads();
    // coalesced copy out: 16B per lane
    int r = tid >> 2;
    size_t orow = (size_t)(bm * 64 + r) * DIM;
    #pragma unroll
    for (int it = 0; it < 8; ++it) {
        int ch = (tid & 3) + it * 4;
        *(u16x8*)&Y[orow + ch * 8] = *(const u16x8*)&smem[r * 256 + ch * 8];
    }
}

// ---------------- edge GEMM: ye[e] = (x[src[e]] @ W[rel]) * rc, coalesced epilogue ----------------
__launch_bounds__(256)
__global__ void k_gemm_edge(const unsigned short* __restrict__ X, const unsigned short* __restrict__ WT,
                            const int* __restrict__ ssrc, const int* __restrict__ stgt,
                            const unsigned int* __restrict__ cnt, const int* __restrict__ blk_rel,
                            unsigned short* __restrict__ ye) {
    int rel = blk_rel[blockIdx.x];
    if (rel < 0) return;
    int base = blockIdx.x * 64;
    const unsigned short* BT = WT + (size_t)rel * DIM * DIM;

    __shared__ __align__(16) unsigned short smem[16384];   // 32 KB
    unsigned short* As0 = smem;
    unsigned short* As1 = smem + 4096;
    int tid = threadIdx.x;
    int wave = tid >> 6, lane = tid & 63;
    int l16 = lane & 15, grp = lane >> 4;
    int arow = tid >> 3, ac16 = tid & 7;

    f32x4 acc[4][4];
    #pragma unroll
    for (int i = 0; i < 4; ++i)
        #pragma unroll
        for (int j = 0; j < 4; ++j) acc[i][j] = f32x4{0.f, 0.f, 0.f, 0.f};

    int s0 = ssrc[base + arow];
    int s1 = ssrc[base + 32 + arow];
    #pragma unroll
    for (int it = 0; it < 2; ++it) {
        int row = it * 32 + arow;
        int s = it ? s1 : s0;
        u16x8 u = {};
        if (s >= 0) u = *(const u16x8*)&X[(size_t)s * DIM + ac16 * 8];
        *(u16x8*)&As0[AS_IDX(row, ac16)] = u;
    }
    for (int kt = 0; kt < 4; ++kt) {
        __syncthreads();
        if (kt < 3) {
            unsigned short* dst = (kt & 1) ? As0 : As1;
            #pragma unroll
            for (int it = 0; it < 2; ++it) {
                int row = it * 32 + arow;
                int s = it ? s1 : s0;
                u16x8 u = {};
                if (s >= 0) u = *(const u16x8*)&X[(size_t)s * DIM + (kt + 1) * 64 + ac16 * 8];
                *(u16x8*)&dst[AS_IDX(row, ac16)] = u;
            }
        }
        const unsigned short* buf = (kt & 1) ? As1 : As0;
        bf16x8 b[2][4];
        #pragma unroll
        for (int kk = 0; kk < 2; ++kk)
            #pragma unroll
            for (int j = 0; j < 4; ++j)
                b[kk][j] = *(const bf16x8*)&BT[(size_t)(wave * 64 + j * 16 + l16) * DIM + kt * 64 + kk * 32 + grp * 8];
        #pragma unroll
        for (int kk = 0; kk < 2; ++kk) {
            bf16x8 a[4];
            #pragma unroll
            for (int i = 0; i < 4; ++i)
                a[i] = *(const bf16x8*)&buf[AS_IDX(i * 16 + l16, kk * 4 + grp)];
            #pragma unroll
            for (int i = 0; i < 4; ++i)
                #pragma unroll
                for (int j = 0; j < 4; ++j)
                    acc[i][j] = __builtin_amdgcn_mfma_f32_16x16x32_bf16(a[i], b[kk][j], acc[i][j], 0, 0, 0);
        }
    }
    __syncthreads();
    // stage scaled output to LDS tile
    #pragma unroll
    for (int i = 0; i < 4; ++i)
        #pragma unroll
        for (int reg = 0; reg < 4; ++reg) {
            int row = i * 16 + grp * 4 + reg;
            int e = base + row;
            int s = ssrc[e];
            int tgt = stgt[e];
            float rc = (s >= 0) ? 1.0f / fmaxf((float)cnt[tgt * NREL + rel], 1.0f) : 0.0f;
            #pragma unroll
            for (int j = 0; j < 4; ++j) {
                int col = wave * 64 + j * 16 + l16;
                float v = acc[i][j][reg] * rc;
                float vo = __shfl_xor(v, 1);
                if (!(lane & 1)) {
                    unsigned pk = (unsigned)f2bf(v) | ((unsigned)f2bf(vo) << 16);
                    *(unsigned*)&smem[row * 256 + col] = pk;
                }
            }
        }
    __syncthreads();
    // coalesced copy out: 16B per lane, skip padded rows
    int r = tid >> 2;
    if (ssrc[base + r] >= 0) {
        size_t orow = (size_t)(base + r) * DIM;
        #pragma unroll
        for (int it = 0; it < 8; ++it) {
            int ch = (tid & 3) + it * 4;
            *(u16x8*)&ye[orow + ch * 8] = *(const u16x8*)&smem[r * 256 + ch * 8];
        }
    }
}

// ---------------- combine: x_out[t] = rootY[t] + sum_{p in CSR[t]} ye[p] (fp32 accum) ----------------
__global__ void k_combine(const unsigned short* __restrict__ rootY, const unsigned short* __restrict__ ye,
                          const int* __restrict__ row_ptr, const int* __restrict__ elist,
                          unsigned short* __restrict__ Xout) {
    int wave = threadIdx.x >> 6, lane = threadIdx.x & 63;
    int tgt = blockIdx.x * 4 + wave;
    int c0 = lane * 4;
    u16x4 rv = *(const u16x4*)&rootY[(size_t)tgt * DIM + c0];
    float a0 = bf2f(rv[0]), a1 = bf2f(rv[1]), a2 = bf2f(rv[2]), a3 = bf2f(rv[3]);
    int p0 = row_ptr[tgt], p1 = row_ptr[tgt + 1];
    for (int p = p0; p < p1; ++p) {
        int idx = elist[p];
        u16x4 v = *(const u16x4*)&ye[(size_t)idx * DIM + c0];
        a0 += bf2f(v[0]); a1 += bf2f(v[1]); a2 += bf2f(v[2]); a3 += bf2f(v[3]);
    }
    u16x4 o;
    o[0] = f2bf(a0); o[1] = f2bf(a1); o[2] = f2bf(a2); o[3] = f2bf(a3);
    *(u16x4*)&Xout[(size_t)tgt * DIM + c0] = o;
}

// ---------------- readout: out[q] += x2[i], run-compressed over sorted batch_ids ----------------
__global__ void k_readout(const unsigned short* __restrict__ X2, const int* __restrict__ bids,
                          float* __restrict__ out) {
    int gid = blockIdx.x * blockDim.x + threadIdx.x;  // 65536 threads
    int g = gid >> 5, c8 = gid & 31;
    int i0 = g * 8;
    float a[8];
    #pragma unroll
    for (int j = 0; j < 8; ++j) a[j] = 0.f;
    int curq = bids[i0];
    #pragma unroll
    for (int t = 0; t < 8; ++t) {
        int i = i0 + t;
        int q = bids[i];
        if (q != curq) {
            #pragma unroll
            for (int j = 0; j < 8; ++j) {
                unsafeAtomicAdd(&out[(size_t)curq * DIM + c8 * 8 + j], a[j]);
                a[j] = 0.f;
            }
            curq = q;
        }
        u16x8 v = *(const u16x8*)&X2[(size_t)i * DIM + c8 * 8];
        #pragma unroll
        for (int j = 0; j < 8; ++j) a[j] += bf2f(v[j]);
    }
    #pragma unroll
    for (int j = 0; j < 8; ++j)
        unsafeAtomicAdd(&out[(size_t)curq * DIM + c8 * 8 + j], a[j]);
}

extern "C" void kernel_launch(void* const* d_in, const int* in_sizes, int n_in,
                              void* d_out, int out_size, void* d_ws, size_t ws_size,
                              hipStream_t stream) {
    const float* emb   = (const float*)d_in[0];
    const float* w1    = (const float*)d_in[1];
    const float* root1 = (const float*)d_in[2];
    const float* b1    = (const float*)d_in[3];
    const float* w2    = (const float*)d_in[4];
    const float* root2 = (const float*)d_in[5];
    const float* b2    = (const float*)d_in[6];
    const int* eidx    = (const int*)d_in[7];
    const int* etype   = (const int*)d_in[8];
    const int* eids    = (const int*)d_in[9];
    const int* bids    = (const int*)d_in[10];
    float* out = (float*)d_out;

    char* ws = (char*)d_ws;
    unsigned short* x0   = (unsigned short*)(ws + (size_t)(0 << 20));   // 8 MB
    unsigned short* x1   = (unsigned short*)(ws + (size_t)(8 << 20));   // 8 MB
    unsigned short* x2   = (unsigned short*)(ws + (size_t)(16 << 20));  // 8 MB
    unsigned short* WT1  = (unsigned short*)(ws + (size_t)(24 << 20));  // 2 MB
    unsigned short* rT1  = (unsigned short*)(ws + (size_t)(26 << 20));  // 128 KB
    unsigned short* WT2  = (unsigned short*)(ws + (size_t)(27 << 20));  // 2 MB
    unsigned short* rT2  = (unsigned short*)(ws + (size_t)(29 << 20));  // 128 KB
    unsigned int*   cnt  = (unsigned int*)(ws + (size_t)(30 << 20));    // 1 MB
    int*           meta  = (int*)(ws + (size_t)(31 << 20));             // 256 B
    int*           ssrc  = (int*)(ws + (size_t)(31 << 20) + 4096);      // 528 KB
    int*           stgt  = (int*)(ws + (size_t)(32 << 20));             // 528 KB
    int*           bh    = (int*)(ws + (size_t)(33 << 20));             // 32 KB
    unsigned int*  cnt_t = (unsigned int*)(ws + (size_t)(33 << 20) + 65536);    // 64 KB
    int*         row_ptr = (int*)(ws + (size_t)(33 << 20) + 2 * 65536);         // 64 KB + 4
    int*           cur_t = (int*)(ws + (size_t)(33 << 20) + 4 * 65536);         // 64 KB
    int*         blk_rel = (int*)(ws + (size_t)(33 << 20) + 6 * 65536);         // 8.3 KB
    int*           elist = (int*)(ws + (size_t)(34 << 20));             // 512 KB
    unsigned short* rootY= (unsigned short*)(ws + (size_t)(35 << 20));  // 8 MB
    unsigned short* ye   = (unsigned short*)(ws + (size_t)(43 << 20));  // 67.6 MB

    hipMemsetAsync(cnt, 0, (size_t)NLOCAL * NREL * 4, stream);
    hipMemsetAsync(cnt_t, 0, (size_t)NLOCAL * 4, stream);
    hipMemsetAsync(ssrc, 0xFF, (size_t)NSLOTS * 4, stream);
    hipMemsetAsync(out, 0, (size_t)NQ * DIM * 4, stream);

    k_gather<<<2048, 256, 0, stream>>>(emb, eids, x0);
    k_transpose_all<<<544, 256, 0, stream>>>(w1, root1, w2, root2, WT1, rT1, WT2, rT2);
    k_hist2<<<NBLKS, 256, 0, stream>>>(eidx, etype, cnt, cnt_t, bh);
    k_scan_all<<<1, 1024, 0, stream>>>(bh, meta, cnt_t, row_ptr, cur_t, blk_rel);
    k_place2<<<NBLKS, 256, 0, stream>>>(eidx, etype, bh, ssrc, stgt, cur_t, elist);

    // layer 1
    k_gemm_root<<<NLOCAL / 64, 256, 0, stream>>>(x0, rT1, b1, rootY);
    k_gemm_edge<<<NBLKE, 256, 0, stream>>>(x0, WT1, ssrc, stgt, cnt, blk_rel, ye);
    k_combine<<<NLOCAL / 4, 256, 0, stream>>>(rootY, ye, row_ptr, elist, x1);
    // layer 2
    k_gemm_root<<<NLOCAL / 64, 256, 0, stream>>>(x1, rT2, b2, rootY);
    k_gemm_edge<<<NBLKE, 256, 0, stream>>>(x1, WT2, ssrc, stgt, cnt, blk_rel, ye);
    k_combine<<<NLOCAL / 4, 256, 0, stream>>>(rootY, ye, row_ptr, elist, x2);

    k_readout<<<256, 256, 0, stream>>>(x2, bids, out);
}

// Round 9
// 465.848 us; speedup vs baseline: 2.0607x; 1.0046x over previous
//
#include <hip/hip_runtime.h>
#include <hip/hip_bf16.h>

#define NLOCAL 16384
#define NEDGES 131072
#define NREL   16
#define DIM    256
#define NQ     4096
#define NBLKS  512                    // NEDGES / 256
#define NSLOTS (NEDGES + NREL * 64)   // 132096 padded slots
#define NBLKE  (NSLOTS / 64)          // 2064 edge-GEMM blocks

typedef __bf16 bf16x8 __attribute__((ext_vector_type(8)));
typedef float  f32x4  __attribute__((ext_vector_type(4)));
typedef unsigned short u16x4 __attribute__((ext_vector_type(4)));
typedef unsigned short u16x8 __attribute__((ext_vector_type(8)));

typedef __attribute__((address_space(1))) const void cglobal_t;
typedef __attribute__((address_space(3))) void clds_t;

static __device__ __forceinline__ unsigned short f2bf(float f) {
    union { float f; unsigned u; } v; v.f = f;
    unsigned r = v.u + 0x7FFFu + ((v.u >> 16) & 1u);
    return (unsigned short)(r >> 16);
}
static __device__ __forceinline__ float bf2f(unsigned short s) {
    union { unsigned u; float f; } v; v.u = ((unsigned)s) << 16;
    return v.f;
}

// ---------------- gather x0 = bf16(emb[entity_ids]) ----------------
__global__ void k_gather(const float* __restrict__ emb, const int* __restrict__ ids,
                         unsigned short* __restrict__ x0) {
    int gid = blockIdx.x * blockDim.x + threadIdx.x;   // 16384*32 threads
    int i = gid >> 5, c8 = gid & 31;
    int e = ids[i];
    const f32x4* src = (const f32x4*)(emb + (size_t)e * DIM + c8 * 8);
    f32x4 a = src[0], b = src[1];
    u16x8 u;
    u[0] = f2bf(a[0]); u[1] = f2bf(a[1]); u[2] = f2bf(a[2]); u[3] = f2bf(a[3]);
    u[4] = f2bf(b[0]); u[5] = f2bf(b[1]); u[6] = f2bf(b[2]); u[7] = f2bf(b[3]);
    *(u16x8*)&x0[(size_t)i * DIM + c8 * 8] = u;
}

// ---------------- transpose+bf16 all weights in one launch ----------------
__global__ void k_transpose_all(const float* __restrict__ w1, const float* __restrict__ r1,
                                const float* __restrict__ w2, const float* __restrict__ r2,
                                unsigned short* __restrict__ WT1, unsigned short* __restrict__ rT1,
                                unsigned short* __restrict__ WT2, unsigned short* __restrict__ rT2) {
    __shared__ float t[64][65];
    int blk = blockIdx.x;
    const float* W; unsigned short* WT; int tr;
    if (blk < 256)      { W = w1 + (size_t)(blk >> 4) * DIM * DIM; WT = WT1 + (size_t)(blk >> 4) * DIM * DIM; tr = blk & 15; }
    else if (blk < 272) { W = r1; WT = rT1; tr = blk - 256; }
    else if (blk < 528) { int q = blk - 272; W = w2 + (size_t)(q >> 4) * DIM * DIM; WT = WT2 + (size_t)(q >> 4) * DIM * DIM; tr = q & 15; }
    else                { W = r2; WT = rT2; tr = blk - 528; }
    int tk = (tr >> 2) << 6;
    int to = (tr & 3) << 6;
    #pragma unroll
    for (int it = 0; it < 16; ++it) {
        int el = it * 256 + threadIdx.x;
        int row = el >> 6, col = el & 63;
        t[row][col] = W[(size_t)(tk + row) * DIM + to + col];
    }
    __syncthreads();
    #pragma unroll
    for (int it = 0; it < 16; ++it) {
        int el = it * 256 + threadIdx.x;
        int row = el >> 6, col = el & 63;
        WT[(size_t)(to + row) * DIM + tk + col] = f2bf(t[col][row]);
    }
}

// ---------------- fused: bucket counts + per-tgt counts + per-block relation histogram ----------------
__global__ void k_hist2(const int* __restrict__ eidx, const int* __restrict__ etype,
                        unsigned int* __restrict__ cnt, unsigned int* __restrict__ cnt_t,
                        int* __restrict__ bh) {
    __shared__ int h[NREL];
    int tid = threadIdx.x;
    if (tid < NREL) h[tid] = 0;
    __syncthreads();
    int e = blockIdx.x * 256 + tid;
    int rel = etype[e];
    int tgt = eidx[NEDGES + e];
    atomicAdd(&cnt[tgt * NREL + rel], 1u);
    atomicAdd(&cnt_t[tgt], 1u);
    atomicAdd(&h[rel], 1);
    __syncthreads();
    if (tid < NREL) bh[tid * NBLKS + blockIdx.x] = h[tid];
}

// ---------------- one kernel: rel-block scan + region bases + blk->rel LUT + tgt CSR scan ----------------
__global__ void k_scan_all(int* __restrict__ bh, int* __restrict__ meta,
                           const unsigned int* __restrict__ cnt_t, int* __restrict__ row_ptr,
                           int* __restrict__ cur_t, int* __restrict__ blk_rel) {
    __shared__ int tot[NREL];
    __shared__ int rs[NREL + 1];
    __shared__ int wsum[16];
    int tid = threadIdx.x;             // 1024 threads
    int w = tid >> 6, lane = tid & 63;

    int vals[8];
    int run = 0;
    #pragma unroll
    for (int c = 0; c < 8; ++c) {
        int v = bh[w * NBLKS + c * 64 + lane];
        int s = v;
        #pragma unroll
        for (int off = 1; off < 64; off <<= 1) {
            int t = __shfl_up(s, off);
            if (lane >= off) s += t;
        }
        vals[c] = run + s - v;
        run += __shfl(s, 63);
    }
    if (lane == 0) tot[w] = run;
    __syncthreads();
    if (tid == 0) {
        int s = 0;
        for (int r = 0; r < NREL; ++r) { rs[r] = s; meta[16 + r] = s; s += (tot[r] + 63) & ~63; }
        rs[NREL] = s; meta[32] = s;
    }
    __syncthreads();
    int b0 = rs[w];
    #pragma unroll
    for (int c = 0; c < 8; ++c) bh[w * NBLKS + c * 64 + lane] = vals[c] + b0;

    int total = rs[NREL];
    for (int b = tid; b < NBLKE; b += 1024) {
        int base = b * 64;
        int r;
        if (base >= total) r = -1;
        else { r = 0; while (r < 15 && rs[r + 1] <= base) ++r; }
        blk_rel[b] = r;
    }

    int base16 = tid * 16;
    int loc[16];
    int s = 0;
    #pragma unroll
    for (int c = 0; c < 16; ++c) { loc[c] = s; s += (int)cnt_t[base16 + c]; }
    int inc = s;
    #pragma unroll
    for (int off = 1; off < 64; off <<= 1) {
        int t = __shfl_up(inc, off);
        if (lane >= off) inc += t;
    }
    if (lane == 63) wsum[w] = inc;
    __syncthreads();
    if (tid == 0) {
        int a = 0;
        for (int q = 0; q < 16; ++q) { int v = wsum[q]; wsum[q] = a; a += v; }
    }
    __syncthreads();
    int excl = wsum[w] + inc - s;
    #pragma unroll
    for (int c = 0; c < 16; ++c) { int v = excl + loc[c]; row_ptr[base16 + c] = v; cur_t[base16 + c] = v; }
    if (tid == 1023) row_ptr[NLOCAL] = excl + s;
}

// ---------------- place edges (rel-sorted) + tgt-CSR fill, one pass ----------------
__global__ void k_place2(const int* __restrict__ eidx, const int* __restrict__ etype,
                         const int* __restrict__ bh, int* __restrict__ ssrc,
                         int* __restrict__ stgt, int* __restrict__ cur_t,
                         int* __restrict__ elist) {
    __shared__ int cur[NREL];
    int tid = threadIdx.x;
    if (tid < NREL) cur[tid] = bh[tid * NBLKS + blockIdx.x];
    __syncthreads();
    int e = blockIdx.x * 256 + tid;
    int rel = etype[e];
    int tgt = eidx[NEDGES + e];
    int pos = atomicAdd(&cur[rel], 1);
    ssrc[pos] = eidx[e];
    stgt[pos] = tgt;
    int q = atomicAdd(&cur_t[tgt], 1);
    elist[q] = pos;
}

// LDS A tile layout: slot(row,cpos) holds global chunk (cpos ^ (row&7)) of row.
// Read of global chunk c16 of row -> LDS idx row*64 + ((c16 ^ (row&7))<<3).
#define AS_IDX(row, c16) ((row) * 64 + (((c16) ^ ((row) & 7)) << 3))

// ---------------- root GEMM: rootY = bf16(X @ rootT^T + bias); async A staging ----------------
__launch_bounds__(256)
__global__ void k_gemm_root(const unsigned short* __restrict__ X, const unsigned short* __restrict__ BT,
                            const float* __restrict__ bias, unsigned short* __restrict__ Y) {
    __shared__ __align__(16) unsigned short As[2][4096];   // 16 KB double-buffered
    int tid = threadIdx.x;
    int wave = tid >> 6, lane = tid & 63;
    int l16 = lane & 15, grp = lane >> 4;
    int bm = blockIdx.x;

    // gload_lds slots: iter it in {0,1}: 16B-slot = (wave*2+it)*64 + lane
    int slot0 = (wave * 2 + 0) * 64 + lane;
    int slot1 = (wave * 2 + 1) * 64 + lane;
    int row0 = slot0 >> 3, cp0 = slot0 & 7;
    int row1 = slot1 >> 3, cp1 = slot1 & 7;
    size_t ga0 = (size_t)(bm * 64 + row0) * DIM + ((cp0 ^ (row0 & 7)) * 8);
    size_t ga1 = (size_t)(bm * 64 + row1) * DIM + ((cp1 ^ (row1 & 7)) * 8);

    f32x4 acc[4][4];
    #pragma unroll
    for (int i = 0; i < 4; ++i)
        #pragma unroll
        for (int j = 0; j < 4; ++j) acc[i][j] = f32x4{0.f, 0.f, 0.f, 0.f};

    // prologue: stage kt=0
    __builtin_amdgcn_global_load_lds((cglobal_t*)(X + ga0), (clds_t*)&As[0][slot0 * 8], 16, 0, 0);
    __builtin_amdgcn_global_load_lds((cglobal_t*)(X + ga1), (clds_t*)&As[0][slot1 * 8], 16, 0, 0);

    for (int kt = 0; kt < 4; ++kt) {
        __syncthreads();   // buffer kt ready (drains outstanding gload_lds)
        if (kt < 3) {
            int nb = (kt + 1) & 1;
            __builtin_amdgcn_global_load_lds((cglobal_t*)(X + ga0 + (kt + 1) * 64), (clds_t*)&As[nb][slot0 * 8], 16, 0, 0);
            __builtin_amdgcn_global_load_lds((cglobal_t*)(X + ga1 + (kt + 1) * 64), (clds_t*)&As[nb][slot1 * 8], 16, 0, 0);
        }
        const unsigned short* buf = As[kt & 1];
        bf16x8 b[2][4];
        #pragma unroll
        for (int kk = 0; kk < 2; ++kk)
            #pragma unroll
            for (int j = 0; j < 4; ++j)
                b[kk][j] = *(const bf16x8*)&BT[(size_t)(wave * 64 + j * 16 + l16) * DIM + kt * 64 + kk * 32 + grp * 8];
        #pragma unroll
        for (int kk = 0; kk < 2; ++kk) {
            bf16x8 a[4];
            #pragma unroll
            for (int i = 0; i < 4; ++i)
                a[i] = *(const bf16x8*)&buf[AS_IDX(i * 16 + l16, kk * 4 + grp)];
            #pragma unroll
            for (int i = 0; i < 4; ++i)
                #pragma unroll
                for (int j = 0; j < 4; ++j)
                    acc[i][j] = __builtin_amdgcn_mfma_f32_16x16x32_bf16(a[i], b[kk][j], acc[i][j], 0, 0, 0);
        }
    }
    #pragma unroll
    for (int i = 0; i < 4; ++i)
        #pragma unroll
        for (int reg = 0; reg < 4; ++reg) {
            int row = i * 16 + grp * 4 + reg;
            int gr = bm * 64 + row;
            #pragma unroll
            for (int j = 0; j < 4; ++j) {
                int col = wave * 64 + j * 16 + l16;
                float v = acc[i][j][reg] + bias[col];
                float vo = __shfl_xor(v, 1);
                if (!(lane & 1)) {
                    unsigned pk = (unsigned)f2bf(v) | ((unsigned)f2bf(vo) << 16);
                    *(unsigned*)&Y[(size_t)gr * DIM + col] = pk;
                }
            }
        }
}

// ---------------- edge GEMM: ye[e] = (x[src[e]] @ W[rel]) * rc; async gathered A staging ----------------
__launch_bounds__(256)
__global__ void k_gemm_edge(const unsigned short* __restrict__ X, const unsigned short* __restrict__ WT,
                            const int* __restrict__ ssrc, const int* __restrict__ stgt,
                            const unsigned int* __restrict__ cnt, const int* __restrict__ blk_rel,
                            unsigned short* __restrict__ ye) {
    int rel = blk_rel[blockIdx.x];
    if (rel < 0) return;
    int base = blockIdx.x * 64;
    const unsigned short* BT = WT + (size_t)rel * DIM * DIM;

    __shared__ __align__(16) unsigned short As[2][4096];   // 16 KB
    int tid = threadIdx.x;
    int wave = tid >> 6, lane = tid & 63;
    int l16 = lane & 15, grp = lane >> 4;

    int slot0 = (wave * 2 + 0) * 64 + lane;
    int slot1 = (wave * 2 + 1) * 64 + lane;
    int row0 = slot0 >> 3, cp0 = slot0 & 7;
    int row1 = slot1 >> 3, cp1 = slot1 & 7;
    int s0 = ssrc[base + row0];
    int s1 = ssrc[base + row1];
    size_t ga0 = (size_t)(s0 < 0 ? 0 : s0) * DIM + ((cp0 ^ (row0 & 7)) * 8);
    size_t ga1 = (size_t)(s1 < 0 ? 0 : s1) * DIM + ((cp1 ^ (row1 & 7)) * 8);

    f32x4 acc[4][4];
    #pragma unroll
    for (int i = 0; i < 4; ++i)
        #pragma unroll
        for (int j = 0; j < 4; ++j) acc[i][j] = f32x4{0.f, 0.f, 0.f, 0.f};

    __builtin_amdgcn_global_load_lds((cglobal_t*)(X + ga0), (clds_t*)&As[0][slot0 * 8], 16, 0, 0);
    __builtin_amdgcn_global_load_lds((cglobal_t*)(X + ga1), (clds_t*)&As[0][slot1 * 8], 16, 0, 0);

    for (int kt = 0; kt < 4; ++kt) {
        __syncthreads();
        if (kt < 3) {
            int nb = (kt + 1) & 1;
            __builtin_amdgcn_global_load_lds((cglobal_t*)(X + ga0 + (kt + 1) * 64), (clds_t*)&As[nb][slot0 * 8], 16, 0, 0);
            __builtin_amdgcn_global_load_lds((cglobal_t*)(X + ga1 + (kt + 1) * 64), (clds_t*)&As[nb][slot1 * 8], 16, 0, 0);
        }
        const unsigned short* buf = As[kt & 1];
        bf16x8 b[2][4];
        #pragma unroll
        for (int kk = 0; kk < 2; ++kk)
            #pragma unroll
            for (int j = 0; j < 4; ++j)
                b[kk][j] = *(const bf16x8*)&BT[(size_t)(wave * 64 + j * 16 + l16) * DIM + kt * 64 + kk * 32 + grp * 8];
        #pragma unroll
        for (int kk = 0; kk < 2; ++kk) {
            bf16x8 a[4];
            #pragma unroll
            for (int i = 0; i < 4; ++i)
                a[i] = *(const bf16x8*)&buf[AS_IDX(i * 16 + l16, kk * 4 + grp)];
            #pragma unroll
            for (int i = 0; i < 4; ++i)
                #pragma unroll
                for (int j = 0; j < 4; ++j)
                    acc[i][j] = __builtin_amdgcn_mfma_f32_16x16x32_bf16(a[i], b[kk][j], acc[i][j], 0, 0, 0);
        }
    }
    #pragma unroll
    for (int i = 0; i < 4; ++i)
        #pragma unroll
        for (int reg = 0; reg < 4; ++reg) {
            int row = i * 16 + grp * 4 + reg;
            int e = base + row;
            int s = ssrc[e];
            int tgt = stgt[e];
            float rc = (s >= 0) ? 1.0f / fmaxf((float)cnt[tgt * NREL + rel], 1.0f) : 0.0f;
            #pragma unroll
            for (int j = 0; j < 4; ++j) {
                int col = wave * 64 + j * 16 + l16;
                float v = acc[i][j][reg] * rc;
                float vo = __shfl_xor(v, 1);
                if (s >= 0 && !(lane & 1)) {
                    unsigned pk = (unsigned)f2bf(v) | ((unsigned)f2bf(vo) << 16);
                    *(unsigned*)&ye[(size_t)e * DIM + col] = pk;
                }
            }
        }
}

// ---------------- combine (layer 1): x_out[t] = rootY[t] + sum ye[p], fp32 accum ----------------
__global__ void k_combine(const unsigned short* __restrict__ rootY, const unsigned short* __restrict__ ye,
                          const int* __restrict__ row_ptr, const int* __restrict__ elist,
                          unsigned short* __restrict__ Xout) {
    int wave = threadIdx.x >> 6, lane = threadIdx.x & 63;
    int tgt = blockIdx.x * 4 + wave;
    int c0 = lane * 4;
    u16x4 rv = *(const u16x4*)&rootY[(size_t)tgt * DIM + c0];
    float a0 = bf2f(rv[0]), a1 = bf2f(rv[1]), a2 = bf2f(rv[2]), a3 = bf2f(rv[3]);
    int p0 = row_ptr[tgt], p1 = row_ptr[tgt + 1];
    for (int p = p0; p < p1; ++p) {
        int idx = elist[p];
        u16x4 v = *(const u16x4*)&ye[(size_t)idx * DIM + c0];
        a0 += bf2f(v[0]); a1 += bf2f(v[1]); a2 += bf2f(v[2]); a3 += bf2f(v[3]);
    }
    u16x4 o;
    o[0] = f2bf(a0); o[1] = f2bf(a1); o[2] = f2bf(a2); o[3] = f2bf(a3);
    *(u16x4*)&Xout[(size_t)tgt * DIM + c0] = o;
}

// ---------------- fused combine(layer2)+readout: out[q] += root[i] + sum ye[p] ----------------
__global__ void k_combine_read(const unsigned short* __restrict__ rootY, const unsigned short* __restrict__ ye,
                               const int* __restrict__ row_ptr, const int* __restrict__ elist,
                               const int* __restrict__ bids, float* __restrict__ out) {
    int gid = blockIdx.x * blockDim.x + threadIdx.x;  // 65536 threads
    int g = gid >> 5, c8 = gid & 31;
    int i0 = g * 8;
    int c0 = c8 * 8;
    float a[8];
    #pragma unroll
    for (int j = 0; j < 8; ++j) a[j] = 0.f;
    int curq = bids[i0];
    #pragma unroll
    for (int t = 0; t < 8; ++t) {
        int i = i0 + t;
        int q = bids[i];
        if (q != curq) {
            #pragma unroll
            for (int j = 0; j < 8; ++j) {
                unsafeAtomicAdd(&out[(size_t)curq * DIM + c0 + j], a[j]);
                a[j] = 0.f;
            }
            curq = q;
        }
        u16x8 rv = *(const u16x8*)&rootY[(size_t)i * DIM + c0];
        #pragma unroll
        for (int j = 0; j < 8; ++j) a[j] += bf2f(rv[j]);
        int p0 = row_ptr[i], p1 = row_ptr[i + 1];
        for (int p = p0; p < p1; ++p) {
            int idx = elist[p];
            u16x8 v = *(const u16x8*)&ye[(size_t)idx * DIM + c0];
            #pragma unroll
            for (int j = 0; j < 8; ++j) a[j] += bf2f(v[j]);
        }
    }
    #pragma unroll
    for (int j = 0; j < 8; ++j)
        unsafeAtomicAdd(&out[(size_t)curq * DIM + c0 + j], a[j]);
}

extern "C" void kernel_launch(void* const* d_in, const int* in_sizes, int n_in,
                              void* d_out, int out_size, void* d_ws, size_t ws_size,
                              hipStream_t stream) {
    const float* emb   = (const float*)d_in[0];
    const float* w1    = (const float*)d_in[1];
    const float* root1 = (const float*)d_in[2];
    const float* b1    = (const float*)d_in[3];
    const float* w2    = (const float*)d_in[4];
    const float* root2 = (const float*)d_in[5];
    const float* b2    = (const float*)d_in[6];
    const int* eidx    = (const int*)d_in[7];
    const int* etype   = (const int*)d_in[8];
    const int* eids    = (const int*)d_in[9];
    const int* bids    = (const int*)d_in[10];
    float* out = (float*)d_out;

    char* ws = (char*)d_ws;
    unsigned short* x0   = (unsigned short*)(ws + (size_t)(0 << 20));   // 8 MB
    unsigned short* x1   = (unsigned short*)(ws + (size_t)(8 << 20));   // 8 MB
    unsigned short* WT1  = (unsigned short*)(ws + (size_t)(24 << 20));  // 2 MB
    unsigned short* rT1  = (unsigned short*)(ws + (size_t)(26 << 20));  // 128 KB
    unsigned short* WT2  = (unsigned short*)(ws + (size_t)(27 << 20));  // 2 MB
    unsigned short* rT2  = (unsigned short*)(ws + (size_t)(29 << 20));  // 128 KB
    unsigned int*   cnt  = (unsigned int*)(ws + (size_t)(30 << 20));    // 1 MB
    int*           meta  = (int*)(ws + (size_t)(31 << 20));             // 256 B
    int*           ssrc  = (int*)(ws + (size_t)(31 << 20) + 4096);      // 528 KB
    int*           stgt  = (int*)(ws + (size_t)(32 << 20));             // 528 KB
    int*           bh    = (int*)(ws + (size_t)(33 << 20));             // 32 KB
    unsigned int*  cnt_t = (unsigned int*)(ws + (size_t)(33 << 20) + 65536);    // 64 KB
    int*         row_ptr = (int*)(ws + (size_t)(33 << 20) + 2 * 65536);         // 64 KB + 4
    int*           cur_t = (int*)(ws + (size_t)(33 << 20) + 4 * 65536);         // 64 KB
    int*         blk_rel = (int*)(ws + (size_t)(33 << 20) + 6 * 65536);         // 8.3 KB
    int*           elist = (int*)(ws + (size_t)(34 << 20));             // 512 KB
    unsigned short* rootY= (unsigned short*)(ws + (size_t)(35 << 20));  // 8 MB
    unsigned short* ye   = (unsigned short*)(ws + (size_t)(43 << 20));  // 67.6 MB

    hipMemsetAsync(cnt, 0, (size_t)NLOCAL * NREL * 4, stream);
    hipMemsetAsync(cnt_t, 0, (size_t)NLOCAL * 4, stream);
    hipMemsetAsync(ssrc, 0xFF, (size_t)NSLOTS * 4, stream);
    hipMemsetAsync(out, 0, (size_t)NQ * DIM * 4, stream);

    k_gather<<<2048, 256, 0, stream>>>(emb, eids, x0);
    k_transpose_all<<<544, 256, 0, stream>>>(w1, root1, w2, root2, WT1, rT1, WT2, rT2);
    k_hist2<<<NBLKS, 256, 0, stream>>>(eidx, etype, cnt, cnt_t, bh);
    k_scan_all<<<1, 1024, 0, stream>>>(bh, meta, cnt_t, row_ptr, cur_t, blk_rel);
    k_place2<<<NBLKS, 256, 0, stream>>>(eidx, etype, bh, ssrc, stgt, cur_t, elist);

    // layer 1
    k_gemm_root<<<NLOCAL / 64, 256, 0, stream>>>(x0, rT1, b1, rootY);
    k_gemm_edge<<<NBLKE, 256, 0, stream>>>(x0, WT1, ssrc, stgt, cnt, blk_rel, ye);
    k_combine<<<NLOCAL / 4, 256, 0, stream>>>(rootY, ye, row_ptr, elist, x1);
    // layer 2
    k_gemm_root<<<NLOCAL / 64, 256, 0, stream>>>(x1, rT2, b2, rootY);
    k_gemm_edge<<<NBLKE, 256, 0, stream>>>(x1, WT2, ssrc, stgt, cnt, blk_rel, ye);
    k_combine_read<<<256, 256, 0, stream>>>(rootY, ye, row_ptr, elist, bids, out);
}